// Round 4
// baseline (262.815 us; speedup 1.0000x reference)
//
#include <hip/hip_runtime.h>
#include <math.h>

#define N_NODES 50000
#define N_EDGES 600000
#define DIM 128
#define HEADS 8
#define NBLK 196
#define DBINS 64
#define EBLK 2344   // (N_EDGES+255)/256
#define GBLK 1563   // (N_NODES+31)/32

typedef _Float16 v8h __attribute__((ext_vector_type(8)));
typedef _Float16 v2h __attribute__((ext_vector_type(2)));
typedef float v16f __attribute__((ext_vector_type(16)));

union v8h_u {
    v8h v;
    v2h p[4];
    _Float16 e[8];
};

__device__ __forceinline__ float dot2(v2h a, v2h b, float c) {
#if __has_builtin(__builtin_amdgcn_fdot2)
    return __builtin_amdgcn_fdot2(a, b, c, false);
#else
    return c + (float)a[0] * (float)b[0] + (float)a[1] * (float)b[1];
#endif
}

// async 16B/lane global->LDS DMA. LDS dest = wave-uniform base + lane*16 (HW rule);
// global src is per-lane. Counted by vmcnt, zero VGPR payload.
__device__ __forceinline__ void dma16(const _Float16* g, _Float16* l) {
    __builtin_amdgcn_global_load_lds(
        (const __attribute__((address_space(1))) unsigned int*)g,
        (__attribute__((address_space(3))) unsigned int*)l, 16, 0, 0);
}

// ---------------- prep: zero counts/bins + W to MFMA-frag layout ----------------
__global__ __launch_bounds__(256) void prep_kernel(const float* __restrict__ Wq,
                                                   const float* __restrict__ Wk,
                                                   const float* __restrict__ Wv,
                                                   const float* __restrict__ Wo,
                                                   _Float16* __restrict__ Wfrag,
                                                   int* __restrict__ counts,
                                                   int* __restrict__ bins) {
    int i = blockIdx.x * 256 + threadIdx.x;
    if (i < N_NODES) counts[i] = 0;
    if (i < DBINS) bins[i] = 0;
    if (i < 16384) {
        int base = i * 4;
        int mat = i >> 12;
        int rem = i & 4095;
        int wave = rem >> 10;
        int kt = (rem >> 7) & 7;
        int lane = (rem >> 1) & 63;
        int jh = (rem & 1) * 4;
        const float* src = (mat == 0) ? Wq : (mat == 1) ? Wk : (mat == 2) ? Wv : Wo;
        int n = wave * 32 + (lane & 31);
        int kbase = kt * 16 + (lane >> 5) * 8 + jh;
        _Float16 o[4];
#pragma unroll
        for (int j = 0; j < 4; j++) o[j] = (_Float16)src[(kbase + j) * 128 + n];
        *(short4*)(Wfrag + base) = *(short4*)o;
    }
}

// ---------------- CSR build ----------------
__global__ __launch_bounds__(256) void hist_kernel(const int* __restrict__ rowi,
                                                   int* __restrict__ counts) {
    int e = blockIdx.x * 256 + threadIdx.x;
    if (e >= N_EDGES) return;
    atomicAdd(counts + rowi[e], 1);
}

__global__ __launch_bounds__(256) void reduce_bins(const int* __restrict__ counts,
                                                   int* __restrict__ partials,
                                                   int* __restrict__ bins) {
    __shared__ int lb[DBINS];
    __shared__ int ws4[4];
    if (threadIdx.x < DBINS) lb[threadIdx.x] = 0;
    __syncthreads();
    int idx = blockIdx.x * 256 + threadIdx.x;
    int v = (idx < N_NODES) ? counts[idx] : 0;
    if (idx < N_NODES) atomicAdd(lb + min(v, DBINS - 1), 1);
    int s = v;
#pragma unroll
    for (int off = 32; off > 0; off >>= 1) s += __shfl_down(s, off);
    if ((threadIdx.x & 63) == 0) ws4[threadIdx.x >> 6] = s;
    __syncthreads();
    if (threadIdx.x == 0) partials[blockIdx.x] = ws4[0] + ws4[1] + ws4[2] + ws4[3];
    if (threadIdx.x < DBINS) {
        int c = lb[threadIdx.x];
        if (c) atomicAdd(bins + threadIdx.x, c);
    }
}

__global__ __launch_bounds__(256) void scan2(const int* __restrict__ partials,
                                             int* __restrict__ offsets,
                                             const int* __restrict__ bins,
                                             int* __restrict__ bptr) {
    __shared__ int sh[256];
    int t = threadIdx.x;
    int v = (t < NBLK) ? partials[t] : 0;
    sh[t] = v;
    __syncthreads();
    for (int off = 1; off < 256; off <<= 1) {
        int a = sh[t];
        int b = (t >= off) ? sh[t - off] : 0;
        __syncthreads();
        sh[t] = a + b;
        __syncthreads();
    }
    if (t < NBLK) offsets[t] = sh[t] - v;  // exclusive
    if (t < 64) {
        int bv = bins[t];
        int bs = bv;
#pragma unroll
        for (int off = 1; off < 64; off <<= 1) {
            int u = __shfl_up(bs, off);
            if (t >= off) bs += u;
        }
        int total = __shfl(bs, 63);
        bptr[t] = total - bs;  // descending: bins > t come first
    }
}

__global__ __launch_bounds__(256) void block_scan(const int* __restrict__ counts,
                                                  const int* __restrict__ offsets,
                                                  int* __restrict__ start,
                                                  int* __restrict__ writeptr) {
    __shared__ int sh[256];
    int t = threadIdx.x;
    int idx = blockIdx.x * 256 + t;
    int v = (idx < N_NODES) ? counts[idx] : 0;
    sh[t] = v;
    __syncthreads();
    for (int off = 1; off < 256; off <<= 1) {
        int a = sh[t];
        int b = (t >= off) ? sh[t - off] : 0;
        __syncthreads();
        sh[t] = a + b;
        __syncthreads();
    }
    if (idx < N_NODES) {
        int s = offsets[blockIdx.x] + sh[t] - v;
        start[idx] = s;
        writeptr[idx] = s;
    }
}

__global__ __launch_bounds__(256) void scatter_all(const int* __restrict__ counts,
                                                   int* __restrict__ bptr,
                                                   int* __restrict__ perm,
                                                   const int* __restrict__ rowi,
                                                   const int* __restrict__ coli,
                                                   const float* __restrict__ eattr,
                                                   int* __restrict__ writeptr,
                                                   int2* __restrict__ ep) {
    if (blockIdx.x < NBLK) {
        __shared__ int lhist[DBINS];
        __shared__ int lbase[DBINS];
        if (threadIdx.x < DBINS) lhist[threadIdx.x] = 0;
        __syncthreads();
        int i = blockIdx.x * 256 + threadIdx.x;
        int b = -1, r = 0;
        if (i < N_NODES) {
            b = min(counts[i], DBINS - 1);
            r = atomicAdd(lhist + b, 1);
        }
        __syncthreads();
        if (threadIdx.x < DBINS) {
            int c = lhist[threadIdx.x];
            lbase[threadIdx.x] = c ? atomicAdd(bptr + threadIdx.x, c) : 0;
        }
        __syncthreads();
        if (b >= 0) perm[lbase[b] + r] = i;
    } else {
        int e = (blockIdx.x - NBLK) * 256 + threadIdx.x;
        if (e >= N_EDGES) return;
        int r = rowi[e];
        int pos = atomicAdd(writeptr + r, 1);
        ep[pos] = make_int2(coli[e], __float_as_int(eattr[e]));
    }
}

// ---------------- fused QKV GEMM: LDS-staged A (f32 x -> f16), 3 outputs ----------------
#define LDSTRIDE 132
__global__ __launch_bounds__(256) void gemm_qkv(const float* __restrict__ x,
                                                const _Float16* __restrict__ Wfrag,
                                                const float* __restrict__ bq,
                                                const float* __restrict__ bk,
                                                const float* __restrict__ bv,
                                                _Float16* __restrict__ Qh,
                                                _Float16* __restrict__ Kh,
                                                _Float16* __restrict__ Vh) {
    __shared__ _Float16 As[32 * LDSTRIDE];
    int tid = threadIdx.x;
    int wave = tid >> 6, lane = tid & 63;
    int m32 = lane & 31, quad = lane >> 5;
    int row0 = blockIdx.x * 32;

    {
        int r = tid >> 3;
        int c0 = (tid & 7) * 16;
        int gr = row0 + r;
        bool valid = gr < N_NODES;
        const float4* src = (const float4*)(x + (size_t)gr * 128 + c0);
        _Float16* dst = As + r * LDSTRIDE + c0;
#pragma unroll
        for (int q = 0; q < 4; q++) {
            float4 v = valid ? src[q] : make_float4(0.f, 0.f, 0.f, 0.f);
            _Float16 o[4] = {(_Float16)v.x, (_Float16)v.y, (_Float16)v.z, (_Float16)v.w};
            *(short4*)(dst + q * 4) = *(short4*)o;
        }
    }
    __syncthreads();

    v8h af[8];
#pragma unroll
    for (int kt = 0; kt < 8; kt++)
        af[kt] = *(const v8h*)(As + m32 * LDSTRIDE + kt * 16 + quad * 8);

    int col = wave * 32 + m32;
#pragma unroll
    for (int mat = 0; mat < 3; mat++) {
        const _Float16* wf = Wfrag + mat * 16384 + wave * 4096 + lane * 8;
        v16f acc;
#pragma unroll
        for (int r = 0; r < 16; r++) acc[r] = 0.0f;
#pragma unroll
        for (int kt = 0; kt < 8; kt++) {
            v8h bf = *(const v8h*)(wf + kt * 512);
            acc = __builtin_amdgcn_mfma_f32_32x32x16_f16(af[kt], bf, acc, 0, 0, 0);
        }
        const float* bias = (mat == 0) ? bq : (mat == 1) ? bk : bv;
        _Float16* C = (mat == 0) ? Qh : (mat == 1) ? Kh : Vh;
        float bias_v = bias[col];
#pragma unroll
        for (int r = 0; r < 16; r++) {
            int row = (r & 3) + 8 * (r >> 2) + 4 * quad;
            int gr = row0 + row;
            if (gr < N_NODES) C[(size_t)gr * 128 + col] = (_Float16)(acc[r] + bias_v);
        }
    }
}

// ---------------- output GEMM: LDS-staged f16 A, f32 out ----------------
__global__ __launch_bounds__(256) void gemm_out(const _Float16* __restrict__ Ah,
                                                const _Float16* __restrict__ Wfrag,
                                                const float* __restrict__ bo,
                                                float* __restrict__ C) {
    __shared__ _Float16 As[32 * LDSTRIDE];
    int tid = threadIdx.x;
    int wave = tid >> 6, lane = tid & 63;
    int m32 = lane & 31, quad = lane >> 5;
    int row0 = blockIdx.x * 32;

    {
        int r = tid >> 3;
        int c0 = (tid & 7) * 16;
        int gr = row0 + r;
        bool valid = gr < N_NODES;
        const v8h* src = (const v8h*)(Ah + (size_t)gr * 128 + c0);
        _Float16* dst = As + r * LDSTRIDE + c0;
        v8h z = {};
        *(v8h*)(dst) = valid ? src[0] : z;
        *(v8h*)(dst + 8) = valid ? src[1] : z;
    }
    __syncthreads();

    v8h af[8];
#pragma unroll
    for (int kt = 0; kt < 8; kt++)
        af[kt] = *(const v8h*)(As + m32 * LDSTRIDE + kt * 16 + quad * 8);

    int col = wave * 32 + m32;
    const _Float16* wf = Wfrag + 3 * 16384 + wave * 4096 + lane * 8;
    v16f acc;
#pragma unroll
    for (int r = 0; r < 16; r++) acc[r] = 0.0f;
#pragma unroll
    for (int kt = 0; kt < 8; kt++) {
        v8h bf = *(const v8h*)(wf + kt * 512);
        acc = __builtin_amdgcn_mfma_f32_32x32x16_f16(af[kt], bf, acc, 0, 0, 0);
    }
    float bias_v = bo[col];
#pragma unroll
    for (int r = 0; r < 16; r++) {
        int row = (r & 3) + 8 * (r >> 2) + 4 * quad;
        int gr = row0 + row;
        if (gr < N_NODES) C[(size_t)gr * 128 + col] = acc[r] + bias_v;
    }
}

// ---------------- fused attention: LDS-DMA ring pipeline (explicit counted vmcnt) ----------------
// R3 failed because there is NO barrier here and the compiler does not track the
// global_load_lds -> ds_read dependency precisely without one (all known-good uses pair
// the DMA with __syncthreads, whose vmcnt(0) drain IS the sync). Fix: explicit counted
// s_waitcnt vmcnt(6) (asm, memory clobber) before each consume, sched_barrier(0)-pinned.
// Count: the fill pair of the consumed slot is followed in pinned order by exactly 3
// later pairs = 6 VMEM ops (any extra interleaved loads only make the wait stricter).
// The memory clobber also forbids CSE of same-address LDS re-reads across refills.
// No-max softmax (range-safe, see R1). Clamped addresses stay in [0,E-1]: finite data,
// predicated ex=0 removes it.
#define ADEPTH 4
__global__ __launch_bounds__(256) void fused_attn(const _Float16* __restrict__ Q,
                                                  const _Float16* __restrict__ K,
                                                  const _Float16* __restrict__ V,
                                                  const int* __restrict__ start,
                                                  const int* __restrict__ counts,
                                                  const int* __restrict__ perm,
                                                  const int2* __restrict__ ep,
                                                  _Float16* __restrict__ Aout) {
    __shared__ _Float16 ring[4][ADEPTH][1024];  // [wave][slot][512 K + 512 V halves] = 32 KB

    int tid = threadIdx.x;
    int wave = tid >> 6, wl = tid & 63;
    int g = wl >> 4, sub = wl & 15;
    int idx = blockIdx.x * 16 + wave * 4 + g;
    bool realnode = idx < N_NODES;
    int n = perm[realnode ? idx : (N_NODES - 1)];

    int s0 = start[n];
    int cnt = realnode ? counts[n] : 0;

    // wave-max degree -> uniform trip count (no divergence around the DMA);
    // perm is degree-sorted so the 4 nodes in a wave have similar degree.
    int wmax = cnt;
    wmax = max(wmax, __shfl_xor(wmax, 16));
    wmax = max(wmax, __shfl_xor(wmax, 32));

    v8h_u q;
    q.v = *(const v8h*)(Q + (size_t)n * 128 + sub * 8);

    float l = 0.0f;
    float acc[8];
#pragma unroll
    for (int j = 0; j < 8; j++) acc[j] = 0.0f;

    // vector ep load for a 16-edge superblock: lane sub holds edge b16+sub (clamped)
    auto ldep = [&](int b16) -> int2 {
        int li = s0 + b16 + sub;
        li = min(li, N_EDGES - 1);
        return ep[li];
    };

    int nsb = (wmax + 15) >> 4;
    int2 pv_cur = ldep(0);

    // prologue: fill slots 0..3 with edges 0..3
#pragma unroll
    for (int d = 0; d < ADEPTH; d++) {
        int col = __shfl(pv_cur.x, d, 16);
        const _Float16* srcK = K + ((size_t)col << 7) + sub * 8;
        const _Float16* srcV = V + ((size_t)col << 7) + sub * 8;
        dma16(srcK, &ring[wave][d][0]);
        dma16(srcV, &ring[wave][d][512]);
    }

    for (int sb = 0; sb < nsb; sb++) {
        int2 pv_next = ldep((sb + 1) << 4);
        int ebase = sb << 4;
#pragma unroll
        for (int u = 0; u < 16; u++) {
            // wait for the DMA pair that filled slot u&3 (3 newer pairs stay in flight)
            __builtin_amdgcn_sched_barrier(0);
            asm volatile("s_waitcnt vmcnt(6)" ::: "memory");
            __builtin_amdgcn_sched_barrier(0);
            v8h_u kk, vv;
            kk.v = *(const v8h*)&ring[wave][u & 3][wl * 8];
            vv.v = *(const v8h*)&ring[wave][u & 3][512 + wl * 8];
            float ea = __int_as_float(__shfl(pv_cur.y, u, 16));
            float dot = 0.0f;
#pragma unroll
            for (int j = 0; j < 4; j++) dot = dot2(q.p[j], kk.p[j], dot);
            dot += __shfl_xor(dot, 1);  // 2 lanes per head
            float s = dot * 0.25f + ea;
            bool valid = (ebase + u) < cnt;
            float ex = valid ? __expf(s) : 0.0f;
            l += ex;
#pragma unroll
            for (int j = 0; j < 8; j++) acc[j] += ex * (float)vv.e[j];
            // refill the just-freed slot with edge ebase+u+4
            int pcol = (u < 12) ? __shfl(pv_cur.x, u + 4, 16)
                                : __shfl(pv_next.x, u - 12, 16);
            const _Float16* srcK = K + ((size_t)pcol << 7) + sub * 8;
            const _Float16* srcV = V + ((size_t)pcol << 7) + sub * 8;
            dma16(srcK, &ring[wave][u & 3][0]);
            dma16(srcV, &ring[wave][u & 3][512]);
        }
        pv_cur = pv_next;
    }

    float inv = 1.0f / (l + 1e-8f);
    _Float16 tmp[8];
#pragma unroll
    for (int j = 0; j < 8; j++) tmp[j] = (_Float16)(acc[j] * inv);
    if (realnode) *(v8h*)(Aout + (size_t)n * 128 + sub * 8) = *(v8h*)tmp;
}

extern "C" void kernel_launch(void* const* d_in, const int* in_sizes, int n_in,
                              void* d_out, int out_size, void* d_ws, size_t ws_size,
                              hipStream_t stream) {
    const float* x = (const float*)d_in[0];
    const int* ei = (const int*)d_in[1];
    const float* eattr = (const float*)d_in[2];
    const float* Wq = (const float*)d_in[3];
    const float* bq = (const float*)d_in[4];
    const float* Wk = (const float*)d_in[5];
    const float* bk = (const float*)d_in[6];
    const float* Wv = (const float*)d_in[7];
    const float* bv = (const float*)d_in[8];
    const float* Wo = (const float*)d_in[9];
    const float* bo = (const float*)d_in[10];
    float* out = (float*)d_out;

    const int* rowi = ei;
    const int* coli = ei + N_EDGES;

    // workspace carve
    _Float16* Qh = (_Float16*)d_ws;
    _Float16* Kh = Qh + (size_t)N_NODES * DIM;
    _Float16* Vh = Kh + (size_t)N_NODES * DIM;
    _Float16* Ah = Vh + (size_t)N_NODES * DIM;
    _Float16* Wfrag = Ah + (size_t)N_NODES * DIM;  // 4*16384 shorts
    int* counts = (int*)(Wfrag + 4 * 16384);
    int* start = counts + N_NODES;
    int* writeptr = start + N_NODES;
    int* partials = writeptr + N_NODES;
    int* offsets = partials + 256;
    int* bins = offsets + 256;
    int* bptr = bins + 64;
    int* perm = bptr + 64;
    int2* ep = (int2*)(perm + N_NODES);

    // prep: zero counts/bins + W frag layout
    prep_kernel<<<NBLK, 256, 0, stream>>>(Wq, Wk, Wv, Wo, Wfrag, counts, bins);
    // CSR build + degree permutation (descending)
    hist_kernel<<<EBLK, 256, 0, stream>>>(rowi, counts);
    reduce_bins<<<NBLK, 256, 0, stream>>>(counts, partials, bins);
    scan2<<<1, 256, 0, stream>>>(partials, offsets, bins, bptr);
    block_scan<<<NBLK, 256, 0, stream>>>(counts, offsets, start, writeptr);
    scatter_all<<<NBLK + EBLK, 256, 0, stream>>>(counts, bptr, perm, rowi, coli, eattr,
                                                 writeptr, ep);

    // fused Q/K/V projection (LDS-staged A, f16 MFMA)
    gemm_qkv<<<GBLK, 256, 0, stream>>>(x, Wfrag, bq, bk, bv, Qh, Kh, Vh);

    // fused gather-attention (16 lanes per node, LDS-DMA ring, counted vmcnt)
    int ablocks = (N_NODES + 15) / 16;
    fused_attn<<<ablocks, 256, 0, stream>>>(Qh, Kh, Vh, start, counts, perm, ep, Ah);

    // output projection
    gemm_out<<<GBLK, 256, 0, stream>>>(Ah, Wfrag, bo, out);
}

// Round 6
// 224.511 us; speedup vs baseline: 1.1706x; 1.1706x over previous
//
#include <hip/hip_runtime.h>
#include <math.h>

#define N_NODES 50000
#define N_EDGES 600000
#define DIM 128
#define HEADS 8
#define NBLK 196
#define DBINS 64
#define EBLK 2344   // (N_EDGES+255)/256
#define GBLK 1563   // (N_NODES+31)/32

typedef _Float16 v8h __attribute__((ext_vector_type(8)));
typedef _Float16 v2h __attribute__((ext_vector_type(2)));
typedef float v16f __attribute__((ext_vector_type(16)));
typedef float v2f __attribute__((ext_vector_type(2)));

union v8h_u {
    v8h v;
    v2h p[4];
    _Float16 e[8];
};

// ---------------- fp8 e4m3 helpers (gfx950 HW cvt; OCP e4m3fn) ----------------
__device__ __forceinline__ float e4m3_to_f32_sw(unsigned int b) {
    unsigned int s = b >> 7, E = (b >> 3) & 0xF, m = b & 7;
    float v = (E == 0) ? (float)m * 0.001953125f
                       : ldexpf(1.0f + (float)m * 0.125f, (int)E - 7);
    return s ? -v : v;
}

template <bool HI>
__device__ __forceinline__ v2f cvt2_f8(unsigned int w) {
#if __has_builtin(__builtin_amdgcn_cvt_pk_f32_fp8)
    return __builtin_amdgcn_cvt_pk_f32_fp8((int)w, HI);
#else
    v2f r;
    r[0] = e4m3_to_f32_sw((w >> (HI ? 16 : 0)) & 0xff);
    r[1] = e4m3_to_f32_sw((w >> (HI ? 24 : 8)) & 0xff);
    return r;
#endif
}

__device__ __forceinline__ unsigned char f32_to_e4m3(float v) {
#if __has_builtin(__builtin_amdgcn_cvt_pk_fp8_f32)
    return (unsigned char)(__builtin_amdgcn_cvt_pk_fp8_f32(v, v, 0, false) & 0xff);
#else
    float a = fabsf(v);
    unsigned char sgn = (v < 0.f) ? 0x80 : 0;
    if (!(a >= 0.0078125f)) {  // below 2^-7: subnormal region
        int m = (int)(a * 512.0f + 0.5f);
        if (m > 7) return sgn | 8;
        return sgn | (unsigned char)m;
    }
    if (a >= 448.0f) return sgn | 0x7e;
    int e;
    float fr = frexpf(a, &e);              // fr in [0.5,1)
    int mant = (int)(fr * 16.0f + 0.5f);   // [8,16]
    int E = e + 6;
    if (mant == 16) { mant = 8; E++; }
    if (E >= 16) return sgn | 0x7e;
    return sgn | (unsigned char)((E << 3) | (mant - 8));
#endif
}

// ---------------- prep: zero counts/bins + W to MFMA-frag layout ----------------
__global__ __launch_bounds__(256) void prep_kernel(const float* __restrict__ Wq,
                                                   const float* __restrict__ Wk,
                                                   const float* __restrict__ Wv,
                                                   const float* __restrict__ Wo,
                                                   _Float16* __restrict__ Wfrag,
                                                   int* __restrict__ counts,
                                                   int* __restrict__ bins) {
    int i = blockIdx.x * 256 + threadIdx.x;
    if (i < N_NODES) counts[i] = 0;
    if (i < DBINS) bins[i] = 0;
    if (i < 16384) {
        int base = i * 4;
        int mat = i >> 12;
        int rem = i & 4095;
        int wave = rem >> 10;
        int kt = (rem >> 7) & 7;
        int lane = (rem >> 1) & 63;
        int jh = (rem & 1) * 4;
        const float* src = (mat == 0) ? Wq : (mat == 1) ? Wk : (mat == 2) ? Wv : Wo;
        int n = wave * 32 + (lane & 31);
        int kbase = kt * 16 + (lane >> 5) * 8 + jh;
        _Float16 o[4];
#pragma unroll
        for (int j = 0; j < 4; j++) o[j] = (_Float16)src[(kbase + j) * 128 + n];
        *(short4*)(Wfrag + base) = *(short4*)o;
    }
}

// ---------------- CSR build ----------------
__global__ __launch_bounds__(256) void hist_kernel(const int* __restrict__ rowi,
                                                   int* __restrict__ counts) {
    int e = blockIdx.x * 256 + threadIdx.x;
    if (e >= N_EDGES) return;
    atomicAdd(counts + rowi[e], 1);
}

__global__ __launch_bounds__(256) void reduce_bins(const int* __restrict__ counts,
                                                   int* __restrict__ partials,
                                                   int* __restrict__ bins) {
    __shared__ int lb[DBINS];
    __shared__ int ws4[4];
    if (threadIdx.x < DBINS) lb[threadIdx.x] = 0;
    __syncthreads();
    int idx = blockIdx.x * 256 + threadIdx.x;
    int v = (idx < N_NODES) ? counts[idx] : 0;
    if (idx < N_NODES) atomicAdd(lb + min(v, DBINS - 1), 1);
    int s = v;
#pragma unroll
    for (int off = 32; off > 0; off >>= 1) s += __shfl_down(s, off);
    if ((threadIdx.x & 63) == 0) ws4[threadIdx.x >> 6] = s;
    __syncthreads();
    if (threadIdx.x == 0) partials[blockIdx.x] = ws4[0] + ws4[1] + ws4[2] + ws4[3];
    if (threadIdx.x < DBINS) {
        int c = lb[threadIdx.x];
        if (c) atomicAdd(bins + threadIdx.x, c);
    }
}

__global__ __launch_bounds__(256) void scan2(const int* __restrict__ partials,
                                             int* __restrict__ offsets,
                                             const int* __restrict__ bins,
                                             int* __restrict__ bptr) {
    __shared__ int sh[256];
    int t = threadIdx.x;
    int v = (t < NBLK) ? partials[t] : 0;
    sh[t] = v;
    __syncthreads();
    for (int off = 1; off < 256; off <<= 1) {
        int a = sh[t];
        int b = (t >= off) ? sh[t - off] : 0;
        __syncthreads();
        sh[t] = a + b;
        __syncthreads();
    }
    if (t < NBLK) offsets[t] = sh[t] - v;  // exclusive
    if (t < 64) {
        int bv = bins[t];
        int bs = bv;
#pragma unroll
        for (int off = 1; off < 64; off <<= 1) {
            int u = __shfl_up(bs, off);
            if (t >= off) bs += u;
        }
        int total = __shfl(bs, 63);
        bptr[t] = total - bs;  // descending: bins > t come first
    }
}

__global__ __launch_bounds__(256) void block_scan(const int* __restrict__ counts,
                                                  const int* __restrict__ offsets,
                                                  int* __restrict__ start,
                                                  int* __restrict__ writeptr) {
    __shared__ int sh[256];
    int t = threadIdx.x;
    int idx = blockIdx.x * 256 + t;
    int v = (idx < N_NODES) ? counts[idx] : 0;
    sh[t] = v;
    __syncthreads();
    for (int off = 1; off < 256; off <<= 1) {
        int a = sh[t];
        int b = (t >= off) ? sh[t - off] : 0;
        __syncthreads();
        sh[t] = a + b;
        __syncthreads();
    }
    if (idx < N_NODES) {
        int s = offsets[blockIdx.x] + sh[t] - v;
        start[idx] = s;
        writeptr[idx] = s;
    }
}

__global__ __launch_bounds__(256) void scatter_all(const int* __restrict__ counts,
                                                   int* __restrict__ bptr,
                                                   int* __restrict__ perm,
                                                   const int* __restrict__ rowi,
                                                   const int* __restrict__ coli,
                                                   const float* __restrict__ eattr,
                                                   int* __restrict__ writeptr,
                                                   int2* __restrict__ ep) {
    if (blockIdx.x < NBLK) {
        __shared__ int lhist[DBINS];
        __shared__ int lbase[DBINS];
        if (threadIdx.x < DBINS) lhist[threadIdx.x] = 0;
        __syncthreads();
        int i = blockIdx.x * 256 + threadIdx.x;
        int b = -1, r = 0;
        if (i < N_NODES) {
            b = min(counts[i], DBINS - 1);
            r = atomicAdd(lhist + b, 1);
        }
        __syncthreads();
        if (threadIdx.x < DBINS) {
            int c = lhist[threadIdx.x];
            lbase[threadIdx.x] = c ? atomicAdd(bptr + threadIdx.x, c) : 0;
        }
        __syncthreads();
        if (b >= 0) perm[lbase[b] + r] = i;
    } else {
        int e = (blockIdx.x - NBLK) * 256 + threadIdx.x;
        if (e >= N_EDGES) return;
        int r = rowi[e];
        int pos = atomicAdd(writeptr + r, 1);
        ep[pos] = make_int2(coli[e], __float_as_int(eattr[e]));
    }
}

// ---------------- fused QKV GEMM: Q,V -> f16, K -> fp8 e4m3 ----------------
#define LDSTRIDE 132
__global__ __launch_bounds__(256) void gemm_qkv(const float* __restrict__ x,
                                                const _Float16* __restrict__ Wfrag,
                                                const float* __restrict__ bq,
                                                const float* __restrict__ bk,
                                                const float* __restrict__ bv,
                                                _Float16* __restrict__ Qh,
                                                unsigned char* __restrict__ K8,
                                                _Float16* __restrict__ Vh) {
    __shared__ _Float16 As[32 * LDSTRIDE];
    int tid = threadIdx.x;
    int wave = tid >> 6, lane = tid & 63;
    int m32 = lane & 31, quad = lane >> 5;
    int row0 = blockIdx.x * 32;

    {
        int r = tid >> 3;
        int c0 = (tid & 7) * 16;
        int gr = row0 + r;
        bool valid = gr < N_NODES;
        const float4* src = (const float4*)(x + (size_t)gr * 128 + c0);
        _Float16* dst = As + r * LDSTRIDE + c0;
#pragma unroll
        for (int q = 0; q < 4; q++) {
            float4 v = valid ? src[q] : make_float4(0.f, 0.f, 0.f, 0.f);
            _Float16 o[4] = {(_Float16)v.x, (_Float16)v.y, (_Float16)v.z, (_Float16)v.w};
            *(short4*)(dst + q * 4) = *(short4*)o;
        }
    }
    __syncthreads();

    v8h af[8];
#pragma unroll
    for (int kt = 0; kt < 8; kt++)
        af[kt] = *(const v8h*)(As + m32 * LDSTRIDE + kt * 16 + quad * 8);

    int col = wave * 32 + m32;
#pragma unroll
    for (int mat = 0; mat < 3; mat++) {
        const _Float16* wf = Wfrag + mat * 16384 + wave * 4096 + lane * 8;
        v16f acc;
#pragma unroll
        for (int r = 0; r < 16; r++) acc[r] = 0.0f;
#pragma unroll
        for (int kt = 0; kt < 8; kt++) {
            v8h bf = *(const v8h*)(wf + kt * 512);
            acc = __builtin_amdgcn_mfma_f32_32x32x16_f16(af[kt], bf, acc, 0, 0, 0);
        }
        const float* bias = (mat == 0) ? bq : (mat == 1) ? bk : bv;
        float bias_v = bias[col];
        if (mat == 1) {
            // K -> fp8 (score-only error; benign, see R5 post-mortem)
#pragma unroll
            for (int r = 0; r < 16; r++) {
                int row = (r & 3) + 8 * (r >> 2) + 4 * quad;
                int gr = row0 + row;
                if (gr < N_NODES) K8[(size_t)gr * 128 + col] = f32_to_e4m3(acc[r] + bias_v);
            }
        } else {
            _Float16* C = (mat == 0) ? Qh : Vh;
#pragma unroll
            for (int r = 0; r < 16; r++) {
                int row = (r & 3) + 8 * (r >> 2) + 4 * quad;
                int gr = row0 + row;
                if (gr < N_NODES) C[(size_t)gr * 128 + col] = (_Float16)(acc[r] + bias_v);
            }
        }
    }
}

// ---------------- output GEMM: LDS-staged f16 A, f32 out ----------------
__global__ __launch_bounds__(256) void gemm_out(const _Float16* __restrict__ Ah,
                                                const _Float16* __restrict__ Wfrag,
                                                const float* __restrict__ bo,
                                                float* __restrict__ C) {
    __shared__ _Float16 As[32 * LDSTRIDE];
    int tid = threadIdx.x;
    int wave = tid >> 6, lane = tid & 63;
    int m32 = lane & 31, quad = lane >> 5;
    int row0 = blockIdx.x * 32;

    {
        int r = tid >> 3;
        int c0 = (tid & 7) * 16;
        int gr = row0 + r;
        bool valid = gr < N_NODES;
        const v8h* src = (const v8h*)(Ah + (size_t)gr * 128 + c0);
        _Float16* dst = As + r * LDSTRIDE + c0;
        v8h z = {};
        *(v8h*)(dst) = valid ? src[0] : z;
        *(v8h*)(dst + 8) = valid ? src[1] : z;
    }
    __syncthreads();

    v8h af[8];
#pragma unroll
    for (int kt = 0; kt < 8; kt++)
        af[kt] = *(const v8h*)(As + m32 * LDSTRIDE + kt * 16 + quad * 8);

    int col = wave * 32 + m32;
    const _Float16* wf = Wfrag + 3 * 16384 + wave * 4096 + lane * 8;
    v16f acc;
#pragma unroll
    for (int r = 0; r < 16; r++) acc[r] = 0.0f;
#pragma unroll
    for (int kt = 0; kt < 8; kt++) {
        v8h bf = *(const v8h*)(wf + kt * 512);
        acc = __builtin_amdgcn_mfma_f32_32x32x16_f16(af[kt], bf, acc, 0, 0, 0);
    }
    float bias_v = bo[col];
#pragma unroll
    for (int r = 0; r < 16; r++) {
        int row = (r & 3) + 8 * (r >> 2) + 4 * quad;
        int gr = row0 + row;
        if (gr < N_NODES) C[(size_t)gr * 128 + col] = acc[r] + bias_v;
    }
}

// ---------------- fused attention: 16 lanes/node, K fp8 + V f16 gather ----------------
// R2 structure. K fp8 halves K-gather bytes (384 B/edge total vs 512). V stays f16:
// R5 showed V-fp8 error passes through UNAVERAGED on low-degree nodes (degree-1 ->
// output = V exactly) and was the 0.031 absmax. K error only perturbs softmax weights
// (zero effect on degree-1 nodes) -> predicted absmax ~0.006.
// Fetch path saturated at ~3.5 TB/s (R0-R4): time ~ bytes.
// no-max softmax (range-safe, R1); tail clamp to THIS node's last edge (e1-1).
__global__ __launch_bounds__(256) void fused_attn(const _Float16* __restrict__ Q,
                                                  const unsigned char* __restrict__ K8,
                                                  const _Float16* __restrict__ V,
                                                  const int* __restrict__ start,
                                                  const int* __restrict__ counts,
                                                  const int* __restrict__ perm,
                                                  const int2* __restrict__ ep,
                                                  _Float16* __restrict__ Aout) {
    int t = blockIdx.x * 256 + threadIdx.x;
    int idx = t >> 4;
    int sub = t & 15;
    if (idx >= N_NODES) return;
    int n = perm[idx];

    int s0 = start[n];
    int cnt = counts[n];
    int e1 = s0 + cnt;

    v8h_u q;
    q.v = *(const v8h*)(Q + (size_t)n * 128 + sub * 8);
    float qf[8];
#pragma unroll
    for (int j = 0; j < 8; j++) qf[j] = (float)q.e[j];

    const unsigned char* Kb = K8 + sub * 8;
    const _Float16* Vb = V + sub * 8;

    float l = 0.0f;
    float acc[8];
#pragma unroll
    for (int j = 0; j < 8; j++) acc[j] = 0.0f;

    int nb = (cnt + 15) >> 4;  // 16-edge super-blocks
    for (int b = 0; b < nb; b++) {
        int base = s0 + (b << 4);
        // vector ep load: lane sub grabs edge base+sub (clamped to THIS node's last edge)
        int li = base + sub;
        if (li >= e1) li = e1 - 1;
        int2 pv = ep[li];

#pragma unroll
        for (int h = 0; h < 2; h++) {
            int hb = h << 3;
            if (base + hb < e1) {
                int cols[8];
                float eas[8];
#pragma unroll
                for (int u = 0; u < 8; u++) {
                    cols[u] = __shfl(pv.x, hb + u, 16);
                    eas[u] = __int_as_float(__shfl(pv.y, hb + u, 16));
                }
                // ---- load phase: 8x8B K + 8x16B V gathers, issued before any compute ----
                uint2 kw[8];
                v8h_u vv[8];
#pragma unroll
                for (int u = 0; u < 8; u++) {
                    kw[u] = *(const uint2*)(Kb + ((size_t)cols[u] << 7));
                    vv[u].v = *(const v8h*)(Vb + ((size_t)cols[u] << 7));
                }
                __builtin_amdgcn_sched_barrier(0);
                // ---- compute phase ----
#pragma unroll
                for (int u = 0; u < 8; u++) {
                    v2f k01 = cvt2_f8<false>(kw[u].x);
                    v2f k23 = cvt2_f8<true>(kw[u].x);
                    v2f k45 = cvt2_f8<false>(kw[u].y);
                    v2f k67 = cvt2_f8<true>(kw[u].y);
                    float dot = 0.0f;
                    dot = fmaf(qf[0], k01[0], dot);
                    dot = fmaf(qf[1], k01[1], dot);
                    dot = fmaf(qf[2], k23[0], dot);
                    dot = fmaf(qf[3], k23[1], dot);
                    dot = fmaf(qf[4], k45[0], dot);
                    dot = fmaf(qf[5], k45[1], dot);
                    dot = fmaf(qf[6], k67[0], dot);
                    dot = fmaf(qf[7], k67[1], dot);
                    dot += __shfl_xor(dot, 1);  // 2 lanes per head
                    float s = dot * 0.25f + eas[u];
                    bool valid = (base + hb + u) < e1;
                    float ex = valid ? __expf(s) : 0.0f;
                    l += ex;
#pragma unroll
                    for (int j = 0; j < 8; j++) acc[j] = fmaf(ex, (float)vv[u].e[j], acc[j]);
                }
            }
        }
    }

    float inv = 1.0f / (l + 1e-8f);
    _Float16 tmp[8];
#pragma unroll
    for (int j = 0; j < 8; j++) tmp[j] = (_Float16)(acc[j] * inv);
    *(v8h*)(Aout + (size_t)n * 128 + sub * 8) = *(v8h*)tmp;
}

extern "C" void kernel_launch(void* const* d_in, const int* in_sizes, int n_in,
                              void* d_out, int out_size, void* d_ws, size_t ws_size,
                              hipStream_t stream) {
    const float* x = (const float*)d_in[0];
    const int* ei = (const int*)d_in[1];
    const float* eattr = (const float*)d_in[2];
    const float* Wq = (const float*)d_in[3];
    const float* bq = (const float*)d_in[4];
    const float* Wk = (const float*)d_in[5];
    const float* bk = (const float*)d_in[6];
    const float* Wv = (const float*)d_in[7];
    const float* bv = (const float*)d_in[8];
    const float* Wo = (const float*)d_in[9];
    const float* bo = (const float*)d_in[10];
    float* out = (float*)d_out;

    const int* rowi = ei;
    const int* coli = ei + N_EDGES;

    // workspace carve
    _Float16* Qh = (_Float16*)d_ws;
    _Float16* Vh = Qh + (size_t)N_NODES * DIM;
    _Float16* Ah = Vh + (size_t)N_NODES * DIM;
    unsigned char* K8 = (unsigned char*)(Ah + (size_t)N_NODES * DIM);
    _Float16* Wfrag = (_Float16*)(K8 + (size_t)N_NODES * DIM);  // 4*16384 shorts
    int* counts = (int*)(Wfrag + 4 * 16384);
    int* start = counts + N_NODES;
    int* writeptr = start + N_NODES;
    int* partials = writeptr + N_NODES;
    int* offsets = partials + 256;
    int* bins = offsets + 256;
    int* bptr = bins + 64;
    int* perm = bptr + 64;
    int2* ep = (int2*)(perm + N_NODES);

    // prep: zero counts/bins + W frag layout
    prep_kernel<<<NBLK, 256, 0, stream>>>(Wq, Wk, Wv, Wo, Wfrag, counts, bins);
    // CSR build + degree permutation (descending)
    hist_kernel<<<EBLK, 256, 0, stream>>>(rowi, counts);
    reduce_bins<<<NBLK, 256, 0, stream>>>(counts, partials, bins);
    scan2<<<1, 256, 0, stream>>>(partials, offsets, bins, bptr);
    block_scan<<<NBLK, 256, 0, stream>>>(counts, offsets, start, writeptr);
    scatter_all<<<NBLK + EBLK, 256, 0, stream>>>(counts, bptr, perm, rowi, coli, eattr,
                                                 writeptr, ep);

    // fused Q/K/V projection (Q,V f16; K fp8)
    gemm_qkv<<<GBLK, 256, 0, stream>>>(x, Wfrag, bq, bk, bv, Qh, K8, Vh);

    // fused gather-attention (16 lanes per node, K fp8 + V f16)
    int ablocks = (N_NODES * 16 + 255) / 256;
    fused_attn<<<ablocks, 256, 0, stream>>>(Qh, K8, Vh, start, counts, perm, ep, Ah);

    // output projection
    gemm_out<<<GBLK, 256, 0, stream>>>(Ah, Wfrag, bo, out);
}

// Round 7
// 195.911 us; speedup vs baseline: 1.3415x; 1.1460x over previous
//
#include <hip/hip_runtime.h>
#include <math.h>

#define N_NODES 50000
#define N_EDGES 600000
#define DIM 128
#define HEADS 8
#define NBLK 196
#define EBLK 2344   // (N_EDGES+255)/256
#define GBLK 1563   // (N_NODES+31)/32

typedef _Float16 v8h __attribute__((ext_vector_type(8)));
typedef _Float16 v2h __attribute__((ext_vector_type(2)));
typedef float v16f __attribute__((ext_vector_type(16)));
typedef float v2f __attribute__((ext_vector_type(2)));

union v8h_u {
    v8h v;
    v2h p[4];
    _Float16 e[8];
};

// ---------------- fp8 e4m3 helpers (gfx950 HW cvt; OCP e4m3fn) ----------------
__device__ __forceinline__ float e4m3_to_f32_sw(unsigned int b) {
    unsigned int s = b >> 7, E = (b >> 3) & 0xF, m = b & 7;
    float v = (E == 0) ? (float)m * 0.001953125f
                       : ldexpf(1.0f + (float)m * 0.125f, (int)E - 7);
    return s ? -v : v;
}

template <bool HI>
__device__ __forceinline__ v2f cvt2_f8(unsigned int w) {
#if __has_builtin(__builtin_amdgcn_cvt_pk_f32_fp8)
    return __builtin_amdgcn_cvt_pk_f32_fp8((int)w, HI);
#else
    v2f r;
    r[0] = e4m3_to_f32_sw((w >> (HI ? 16 : 0)) & 0xff);
    r[1] = e4m3_to_f32_sw((w >> (HI ? 24 : 8)) & 0xff);
    return r;
#endif
}

__device__ __forceinline__ unsigned char f32_to_e4m3(float v) {
#if __has_builtin(__builtin_amdgcn_cvt_pk_fp8_f32)
    return (unsigned char)(__builtin_amdgcn_cvt_pk_fp8_f32(v, v, 0, false) & 0xff);
#else
    float a = fabsf(v);
    unsigned char sgn = (v < 0.f) ? 0x80 : 0;
    if (!(a >= 0.0078125f)) {
        int m = (int)(a * 512.0f + 0.5f);
        if (m > 7) return sgn | 8;
        return sgn | (unsigned char)m;
    }
    if (a >= 448.0f) return sgn | 0x7e;
    int e;
    float fr = frexpf(a, &e);
    int mant = (int)(fr * 16.0f + 0.5f);
    int E = e + 6;
    if (mant == 16) { mant = 8; E++; }
    if (E >= 16) return sgn | 0x7e;
    return sgn | (unsigned char)((E << 3) | (mant - 8));
#endif
}

// ---------------- prep: zero counts/cursor + W to MFMA-frag layout ----------------
__global__ __launch_bounds__(256) void prep_kernel(const float* __restrict__ Wq,
                                                   const float* __restrict__ Wk,
                                                   const float* __restrict__ Wv,
                                                   const float* __restrict__ Wo,
                                                   _Float16* __restrict__ Wfrag,
                                                   int* __restrict__ counts,
                                                   int* __restrict__ cursor) {
    int i = blockIdx.x * 256 + threadIdx.x;
    if (i < N_NODES) counts[i] = 0;
    if (i == 0) cursor[0] = 0;
    if (i < 16384) {
        int base = i * 4;
        int mat = i >> 12;
        int rem = i & 4095;
        int wave = rem >> 10;
        int kt = (rem >> 7) & 7;
        int lane = (rem >> 1) & 63;
        int jh = (rem & 1) * 4;
        const float* src = (mat == 0) ? Wq : (mat == 1) ? Wk : (mat == 2) ? Wv : Wo;
        int n = wave * 32 + (lane & 31);
        int kbase = kt * 16 + (lane >> 5) * 8 + jh;
        _Float16 o[4];
#pragma unroll
        for (int j = 0; j < 4; j++) o[j] = (_Float16)src[(kbase + j) * 128 + n];
        *(short4*)(Wfrag + base) = *(short4*)o;
    }
}

// ---------------- fused QKV GEMM + edge histogram (independent work, one launch) ----
// blocks [0, GBLK): QKV projection (Q,V f16; K fp8)
// blocks [GBLK, GBLK+EBLK): hist with rank capture: rank[e] = old count of row
#define LDSTRIDE 132
__global__ __launch_bounds__(256) void qkv_hist(const float* __restrict__ x,
                                                const _Float16* __restrict__ Wfrag,
                                                const float* __restrict__ bq,
                                                const float* __restrict__ bk,
                                                const float* __restrict__ bv,
                                                _Float16* __restrict__ Qh,
                                                unsigned char* __restrict__ K8,
                                                _Float16* __restrict__ Vh,
                                                const int* __restrict__ rowi,
                                                int* __restrict__ counts,
                                                int* __restrict__ rank) {
    __shared__ _Float16 As[32 * LDSTRIDE];
    if (blockIdx.x >= GBLK) {
        int e = (blockIdx.x - GBLK) * 256 + threadIdx.x;
        if (e < N_EDGES) rank[e] = atomicAdd(counts + rowi[e], 1);
        return;
    }
    int tid = threadIdx.x;
    int wave = tid >> 6, lane = tid & 63;
    int m32 = lane & 31, quad = lane >> 5;
    int row0 = blockIdx.x * 32;

    {
        int r = tid >> 3;
        int c0 = (tid & 7) * 16;
        int gr = row0 + r;
        bool valid = gr < N_NODES;
        const float4* src = (const float4*)(x + (size_t)gr * 128 + c0);
        _Float16* dst = As + r * LDSTRIDE + c0;
#pragma unroll
        for (int q = 0; q < 4; q++) {
            float4 v = valid ? src[q] : make_float4(0.f, 0.f, 0.f, 0.f);
            _Float16 o[4] = {(_Float16)v.x, (_Float16)v.y, (_Float16)v.z, (_Float16)v.w};
            *(short4*)(dst + q * 4) = *(short4*)o;
        }
    }
    __syncthreads();

    v8h af[8];
#pragma unroll
    for (int kt = 0; kt < 8; kt++)
        af[kt] = *(const v8h*)(As + m32 * LDSTRIDE + kt * 16 + quad * 8);

    int col = wave * 32 + m32;
#pragma unroll
    for (int mat = 0; mat < 3; mat++) {
        const _Float16* wf = Wfrag + mat * 16384 + wave * 4096 + lane * 8;
        v16f acc;
#pragma unroll
        for (int r = 0; r < 16; r++) acc[r] = 0.0f;
#pragma unroll
        for (int kt = 0; kt < 8; kt++) {
            v8h bf = *(const v8h*)(wf + kt * 512);
            acc = __builtin_amdgcn_mfma_f32_32x32x16_f16(af[kt], bf, acc, 0, 0, 0);
        }
        const float* bias = (mat == 0) ? bq : (mat == 1) ? bk : bv;
        float bias_v = bias[col];
        if (mat == 1) {
#pragma unroll
            for (int r = 0; r < 16; r++) {
                int row = (r & 3) + 8 * (r >> 2) + 4 * quad;
                int gr = row0 + row;
                if (gr < N_NODES) K8[(size_t)gr * 128 + col] = f32_to_e4m3(acc[r] + bias_v);
            }
        } else {
            _Float16* C = (mat == 0) ? Qh : Vh;
#pragma unroll
            for (int r = 0; r < 16; r++) {
                int row = (r & 3) + 8 * (r >> 2) + 4 * quad;
                int gr = row0 + row;
                if (gr < N_NODES) C[(size_t)gr * 128 + col] = (_Float16)(acc[r] + bias_v);
            }
        }
    }
}

// ---------------- segment allocation: block LDS scan + one cursor atomic per block ----
// Node segments need not be in node order -> order-free cursor allocation replaces
// the 3-kernel global scan (reduce_bins/scan2/block_scan) and the degree perm.
__global__ __launch_bounds__(256) void alloc_scan(const int* __restrict__ counts,
                                                  int* __restrict__ start,
                                                  int* __restrict__ cursor) {
    __shared__ int sh[256];
    __shared__ int base;
    int t = threadIdx.x;
    int idx = blockIdx.x * 256 + t;
    int v = (idx < N_NODES) ? counts[idx] : 0;
    sh[t] = v;
    __syncthreads();
    for (int off = 1; off < 256; off <<= 1) {
        int a = sh[t];
        int b = (t >= off) ? sh[t - off] : 0;
        __syncthreads();
        sh[t] = a + b;
        __syncthreads();
    }
    if (t == 255) base = atomicAdd(cursor, sh[255]);
    __syncthreads();
    if (idx < N_NODES) start[idx] = base + sh[t] - v;
}

// ---------------- scatter: atomic-free (pos = start[row] + rank[edge]) ----------------
__global__ __launch_bounds__(256) void scatter_k(const int* __restrict__ rowi,
                                                 const int* __restrict__ coli,
                                                 const float* __restrict__ eattr,
                                                 const int* __restrict__ start,
                                                 const int* __restrict__ rank,
                                                 int2* __restrict__ ep) {
    int e = blockIdx.x * 256 + threadIdx.x;
    if (e >= N_EDGES) return;
    int pos = start[rowi[e]] + rank[e];
    ep[pos] = make_int2(coli[e], __float_as_int(eattr[e]));
}

// ---------------- output GEMM: LDS-staged f16 A, f32 out ----------------
__global__ __launch_bounds__(256) void gemm_out(const _Float16* __restrict__ Ah,
                                                const _Float16* __restrict__ Wfrag,
                                                const float* __restrict__ bo,
                                                float* __restrict__ C) {
    __shared__ _Float16 As[32 * LDSTRIDE];
    int tid = threadIdx.x;
    int wave = tid >> 6, lane = tid & 63;
    int m32 = lane & 31, quad = lane >> 5;
    int row0 = blockIdx.x * 32;

    {
        int r = tid >> 3;
        int c0 = (tid & 7) * 16;
        int gr = row0 + r;
        bool valid = gr < N_NODES;
        const v8h* src = (const v8h*)(Ah + (size_t)gr * 128 + c0);
        _Float16* dst = As + r * LDSTRIDE + c0;
        v8h z = {};
        *(v8h*)(dst) = valid ? src[0] : z;
        *(v8h*)(dst + 8) = valid ? src[1] : z;
    }
    __syncthreads();

    v8h af[8];
#pragma unroll
    for (int kt = 0; kt < 8; kt++)
        af[kt] = *(const v8h*)(As + m32 * LDSTRIDE + kt * 16 + quad * 8);

    int col = wave * 32 + m32;
    const _Float16* wf = Wfrag + 3 * 16384 + wave * 4096 + lane * 8;
    v16f acc;
#pragma unroll
    for (int r = 0; r < 16; r++) acc[r] = 0.0f;
#pragma unroll
    for (int kt = 0; kt < 8; kt++) {
        v8h bf = *(const v8h*)(wf + kt * 512);
        acc = __builtin_amdgcn_mfma_f32_32x32x16_f16(af[kt], bf, acc, 0, 0, 0);
    }
    float bias_v = bo[col];
#pragma unroll
    for (int r = 0; r < 16; r++) {
        int row = (r & 3) + 8 * (r >> 2) + 4 * quad;
        int gr = row0 + row;
        if (gr < N_NODES) C[(size_t)gr * 128 + col] = acc[r] + bias_v;
    }
}

// ---------------- fused attention: 16 lanes/node (identity order), K fp8 + V f16 ------
// R2 structure, K fp8 (R6: absmax 0.0098, passes). Identity node order: Q/ep reads
// coalesced; degree divergence costs only clamped L2-hit loads (byte-bound kernel).
// no-max softmax (range-safe, R1); tail clamp to THIS node's last edge (e1-1).
__global__ __launch_bounds__(256) void fused_attn(const _Float16* __restrict__ Q,
                                                  const unsigned char* __restrict__ K8,
                                                  const _Float16* __restrict__ V,
                                                  const int* __restrict__ start,
                                                  const int* __restrict__ counts,
                                                  const int2* __restrict__ ep,
                                                  _Float16* __restrict__ Aout) {
    int t = blockIdx.x * 256 + threadIdx.x;
    int n = t >> 4;
    int sub = t & 15;
    if (n >= N_NODES) return;

    int s0 = start[n];
    int cnt = counts[n];
    int e1 = s0 + cnt;

    v8h_u q;
    q.v = *(const v8h*)(Q + (size_t)n * 128 + sub * 8);
    float qf[8];
#pragma unroll
    for (int j = 0; j < 8; j++) qf[j] = (float)q.e[j];

    const unsigned char* Kb = K8 + sub * 8;
    const _Float16* Vb = V + sub * 8;

    float l = 0.0f;
    float acc[8];
#pragma unroll
    for (int j = 0; j < 8; j++) acc[j] = 0.0f;

    int nb = (cnt + 15) >> 4;  // 16-edge super-blocks
    for (int b = 0; b < nb; b++) {
        int base = s0 + (b << 4);
        int li = base + sub;
        if (li >= e1) li = e1 - 1;
        int2 pv = ep[li];

#pragma unroll
        for (int h = 0; h < 2; h++) {
            int hb = h << 3;
            if (base + hb < e1) {
                int cols[8];
                float eas[8];
#pragma unroll
                for (int u = 0; u < 8; u++) {
                    cols[u] = __shfl(pv.x, hb + u, 16);
                    eas[u] = __int_as_float(__shfl(pv.y, hb + u, 16));
                }
                // ---- load phase: 8x8B K + 8x16B V gathers, issued before any compute ----
                uint2 kw[8];
                v8h_u vv[8];
#pragma unroll
                for (int u = 0; u < 8; u++) {
                    kw[u] = *(const uint2*)(Kb + ((size_t)cols[u] << 7));
                    vv[u].v = *(const v8h*)(Vb + ((size_t)cols[u] << 7));
                }
                __builtin_amdgcn_sched_barrier(0);
                // ---- compute phase ----
#pragma unroll
                for (int u = 0; u < 8; u++) {
                    v2f k01 = cvt2_f8<false>(kw[u].x);
                    v2f k23 = cvt2_f8<true>(kw[u].x);
                    v2f k45 = cvt2_f8<false>(kw[u].y);
                    v2f k67 = cvt2_f8<true>(kw[u].y);
                    float dot = 0.0f;
                    dot = fmaf(qf[0], k01[0], dot);
                    dot = fmaf(qf[1], k01[1], dot);
                    dot = fmaf(qf[2], k23[0], dot);
                    dot = fmaf(qf[3], k23[1], dot);
                    dot = fmaf(qf[4], k45[0], dot);
                    dot = fmaf(qf[5], k45[1], dot);
                    dot = fmaf(qf[6], k67[0], dot);
                    dot = fmaf(qf[7], k67[1], dot);
                    dot += __shfl_xor(dot, 1);  // 2 lanes per head
                    float s = dot * 0.25f + eas[u];
                    bool valid = (base + hb + u) < e1;
                    float ex = valid ? __expf(s) : 0.0f;
                    l += ex;
#pragma unroll
                    for (int j = 0; j < 8; j++) acc[j] = fmaf(ex, (float)vv[u].e[j], acc[j]);
                }
            }
        }
    }

    float inv = 1.0f / (l + 1e-8f);
    _Float16 tmp[8];
#pragma unroll
    for (int j = 0; j < 8; j++) tmp[j] = (_Float16)(acc[j] * inv);
    *(v8h*)(Aout + (size_t)n * 128 + sub * 8) = *(v8h*)tmp;
}

extern "C" void kernel_launch(void* const* d_in, const int* in_sizes, int n_in,
                              void* d_out, int out_size, void* d_ws, size_t ws_size,
                              hipStream_t stream) {
    const float* x = (const float*)d_in[0];
    const int* ei = (const int*)d_in[1];
    const float* eattr = (const float*)d_in[2];
    const float* Wq = (const float*)d_in[3];
    const float* bq = (const float*)d_in[4];
    const float* Wk = (const float*)d_in[5];
    const float* bk = (const float*)d_in[6];
    const float* Wv = (const float*)d_in[7];
    const float* bv = (const float*)d_in[8];
    const float* Wo = (const float*)d_in[9];
    const float* bo = (const float*)d_in[10];
    float* out = (float*)d_out;

    const int* rowi = ei;
    const int* coli = ei + N_EDGES;

    // workspace carve
    _Float16* Qh = (_Float16*)d_ws;
    _Float16* Vh = Qh + (size_t)N_NODES * DIM;
    _Float16* Ah = Vh + (size_t)N_NODES * DIM;
    unsigned char* K8 = (unsigned char*)(Ah + (size_t)N_NODES * DIM);
    _Float16* Wfrag = (_Float16*)(K8 + (size_t)N_NODES * DIM);  // 4*16384 shorts
    int* counts = (int*)(Wfrag + 4 * 16384);
    int* start = counts + N_NODES;
    int* rank = start + N_NODES;
    int* cursor = rank + N_EDGES;  // 1 int (+1 pad keeps ep 8B-aligned)
    int2* ep = (int2*)(cursor + 2);

    // 1. prep: zero counts/cursor + W frag layout
    prep_kernel<<<NBLK, 256, 0, stream>>>(Wq, Wk, Wv, Wo, Wfrag, counts, cursor);
    // 2. QKV projection || edge histogram (rank capture)
    qkv_hist<<<GBLK + EBLK, 256, 0, stream>>>(x, Wfrag, bq, bk, bv, Qh, K8, Vh,
                                              rowi, counts, rank);
    // 3. order-free segment allocation (block scan + cursor atomic)
    alloc_scan<<<NBLK, 256, 0, stream>>>(counts, start, cursor);
    // 4. atomic-free scatter
    scatter_k<<<EBLK, 256, 0, stream>>>(rowi, coli, eattr, start, rank, ep);
    // 5. fused gather-attention (16 lanes per node, K fp8 + V f16)
    int ablocks = (N_NODES * 16 + 255) / 256;
    fused_attn<<<ablocks, 256, 0, stream>>>(Qh, K8, Vh, start, counts, ep, Ah);
    // 6. output projection
    gemm_out<<<GBLK, 256, 0, stream>>>(Ah, Wfrag, bo, out);
}

// Round 8
// 191.538 us; speedup vs baseline: 1.3721x; 1.0228x over previous
//
#include <hip/hip_runtime.h>
#include <math.h>

#define N_NODES 50000
#define N_EDGES 600000
#define DIM 128
#define HEADS 8
#define NBLK 196
#define EBLK 2344   // (N_EDGES+255)/256
#define HBLK 586    // (N_EDGES+1023)/1024, 4 edges/thread
#define GBLK 1563   // (N_NODES+31)/32

typedef _Float16 v8h __attribute__((ext_vector_type(8)));
typedef _Float16 v2h __attribute__((ext_vector_type(2)));
typedef float v16f __attribute__((ext_vector_type(16)));
typedef float v2f __attribute__((ext_vector_type(2)));

union v8h_u {
    v8h v;
    v2h p[4];
    _Float16 e[8];
};

// ---------------- fp8 e4m3 helpers (gfx950 HW cvt; OCP e4m3fn) ----------------
__device__ __forceinline__ float e4m3_to_f32_sw(unsigned int b) {
    unsigned int s = b >> 7, E = (b >> 3) & 0xF, m = b & 7;
    float v = (E == 0) ? (float)m * 0.001953125f
                       : ldexpf(1.0f + (float)m * 0.125f, (int)E - 7);
    return s ? -v : v;
}

template <bool HI>
__device__ __forceinline__ v2f cvt2_f8(unsigned int w) {
#if __has_builtin(__builtin_amdgcn_cvt_pk_f32_fp8)
    return __builtin_amdgcn_cvt_pk_f32_fp8((int)w, HI);
#else
    v2f r;
    r[0] = e4m3_to_f32_sw((w >> (HI ? 16 : 0)) & 0xff);
    r[1] = e4m3_to_f32_sw((w >> (HI ? 24 : 8)) & 0xff);
    return r;
#endif
}

__device__ __forceinline__ unsigned char f32_to_e4m3(float v) {
#if __has_builtin(__builtin_amdgcn_cvt_pk_fp8_f32)
    return (unsigned char)(__builtin_amdgcn_cvt_pk_fp8_f32(v, v, 0, false) & 0xff);
#else
    float a = fabsf(v);
    unsigned char sgn = (v < 0.f) ? 0x80 : 0;
    if (!(a >= 0.0078125f)) {
        int m = (int)(a * 512.0f + 0.5f);
        if (m > 7) return sgn | 8;
        return sgn | (unsigned char)m;
    }
    if (a >= 448.0f) return sgn | 0x7e;
    int e;
    float fr = frexpf(a, &e);
    int mant = (int)(fr * 16.0f + 0.5f);
    int E = e + 6;
    if (mant == 16) { mant = 8; E++; }
    if (E >= 16) return sgn | 0x7e;
    return sgn | (unsigned char)((E << 3) | (mant - 8));
#endif
}

// ---------------- prep: zero counts/cursor + W to MFMA-frag layout ----------------
__global__ __launch_bounds__(256) void prep_kernel(const float* __restrict__ Wq,
                                                   const float* __restrict__ Wk,
                                                   const float* __restrict__ Wv,
                                                   const float* __restrict__ Wo,
                                                   _Float16* __restrict__ Wfrag,
                                                   int* __restrict__ counts,
                                                   int* __restrict__ cursor) {
    int i = blockIdx.x * 256 + threadIdx.x;
    if (i < N_NODES) counts[i] = 0;
    if (i == 0) cursor[0] = 0;
    if (i < 16384) {
        int base = i * 4;
        int mat = i >> 12;
        int rem = i & 4095;
        int wave = rem >> 10;
        int kt = (rem >> 7) & 7;
        int lane = (rem >> 1) & 63;
        int jh = (rem & 1) * 4;
        const float* src = (mat == 0) ? Wq : (mat == 1) ? Wk : (mat == 2) ? Wv : Wo;
        int n = wave * 32 + (lane & 31);
        int kbase = kt * 16 + (lane >> 5) * 8 + jh;
        _Float16 o[4];
#pragma unroll
        for (int j = 0; j < 4; j++) o[j] = (_Float16)src[(kbase + j) * 128 + n];
        *(short4*)(Wfrag + base) = *(short4*)o;
    }
}

// ---------------- fused QKV GEMM + edge histogram (independent work, one launch) ----
// blocks [0, GBLK): QKV projection (Q,V f16; K fp8)
// blocks [GBLK, GBLK+HBLK): hist, 4 edges/thread -> 4 independent return-atomics
// in flight per thread (MLP test: latency-bound hist should compress ~4x).
#define LDSTRIDE 132
__global__ __launch_bounds__(256) void qkv_hist(const float* __restrict__ x,
                                                const _Float16* __restrict__ Wfrag,
                                                const float* __restrict__ bq,
                                                const float* __restrict__ bk,
                                                const float* __restrict__ bv,
                                                _Float16* __restrict__ Qh,
                                                unsigned char* __restrict__ K8,
                                                _Float16* __restrict__ Vh,
                                                const int* __restrict__ rowi,
                                                int* __restrict__ counts,
                                                int* __restrict__ rank) {
    __shared__ _Float16 As[32 * LDSTRIDE];
    if (blockIdx.x >= GBLK) {
        int e0 = (blockIdx.x - GBLK) * 1024 + threadIdx.x;
        int r[4], rk[4];
#pragma unroll
        for (int k = 0; k < 4; k++) {
            int e = e0 + k * 256;
            r[k] = (e < N_EDGES) ? rowi[e] : -1;
        }
#pragma unroll
        for (int k = 0; k < 4; k++)
            if (r[k] >= 0) rk[k] = atomicAdd(counts + r[k], 1);
#pragma unroll
        for (int k = 0; k < 4; k++) {
            int e = e0 + k * 256;
            if (e < N_EDGES) rank[e] = rk[k];
        }
        return;
    }
    int tid = threadIdx.x;
    int wave = tid >> 6, lane = tid & 63;
    int m32 = lane & 31, quad = lane >> 5;
    int row0 = blockIdx.x * 32;

    {
        int r = tid >> 3;
        int c0 = (tid & 7) * 16;
        int gr = row0 + r;
        bool valid = gr < N_NODES;
        const float4* src = (const float4*)(x + (size_t)gr * 128 + c0);
        _Float16* dst = As + r * LDSTRIDE + c0;
#pragma unroll
        for (int q = 0; q < 4; q++) {
            float4 v = valid ? src[q] : make_float4(0.f, 0.f, 0.f, 0.f);
            _Float16 o[4] = {(_Float16)v.x, (_Float16)v.y, (_Float16)v.z, (_Float16)v.w};
            *(short4*)(dst + q * 4) = *(short4*)o;
        }
    }
    __syncthreads();

    v8h af[8];
#pragma unroll
    for (int kt = 0; kt < 8; kt++)
        af[kt] = *(const v8h*)(As + m32 * LDSTRIDE + kt * 16 + quad * 8);

    int col = wave * 32 + m32;
#pragma unroll
    for (int mat = 0; mat < 3; mat++) {
        const _Float16* wf = Wfrag + mat * 16384 + wave * 4096 + lane * 8;
        v16f acc;
#pragma unroll
        for (int r = 0; r < 16; r++) acc[r] = 0.0f;
#pragma unroll
        for (int kt = 0; kt < 8; kt++) {
            v8h bf = *(const v8h*)(wf + kt * 512);
            acc = __builtin_amdgcn_mfma_f32_32x32x16_f16(af[kt], bf, acc, 0, 0, 0);
        }
        const float* bias = (mat == 0) ? bq : (mat == 1) ? bk : bv;
        float bias_v = bias[col];
        if (mat == 1) {
#pragma unroll
            for (int r = 0; r < 16; r++) {
                int row = (r & 3) + 8 * (r >> 2) + 4 * quad;
                int gr = row0 + row;
                if (gr < N_NODES) K8[(size_t)gr * 128 + col] = f32_to_e4m3(acc[r] + bias_v);
            }
        } else {
            _Float16* C = (mat == 0) ? Qh : Vh;
#pragma unroll
            for (int r = 0; r < 16; r++) {
                int row = (r & 3) + 8 * (r >> 2) + 4 * quad;
                int gr = row0 + row;
                if (gr < N_NODES) C[(size_t)gr * 128 + col] = (_Float16)(acc[r] + bias_v);
            }
        }
    }
}

// ---------------- segment allocation: block LDS scan + one cursor atomic per block ----
__global__ __launch_bounds__(256) void alloc_scan(const int* __restrict__ counts,
                                                  int* __restrict__ start,
                                                  int* __restrict__ cursor) {
    __shared__ int sh[256];
    __shared__ int base;
    int t = threadIdx.x;
    int idx = blockIdx.x * 256 + t;
    int v = (idx < N_NODES) ? counts[idx] : 0;
    sh[t] = v;
    __syncthreads();
    for (int off = 1; off < 256; off <<= 1) {
        int a = sh[t];
        int b = (t >= off) ? sh[t - off] : 0;
        __syncthreads();
        sh[t] = a + b;
        __syncthreads();
    }
    if (t == 255) base = atomicAdd(cursor, sh[255]);
    __syncthreads();
    if (idx < N_NODES) start[idx] = base + sh[t] - v;
}

// ---------------- scatter: atomic-free, packed 4B edge records ----------------
// ep4[pos] = u16 col | (f16 eattr << 16). 50000 < 65536 so col fits u16;
// f16 eattr adds ~5e-4 score noise (negligible vs accepted fp8-K noise).
__global__ __launch_bounds__(256) void scatter_k(const int* __restrict__ rowi,
                                                 const int* __restrict__ coli,
                                                 const float* __restrict__ eattr,
                                                 const int* __restrict__ start,
                                                 const int* __restrict__ rank,
                                                 unsigned int* __restrict__ ep4) {
    int e = blockIdx.x * 256 + threadIdx.x;
    if (e >= N_EDGES) return;
    int pos = start[rowi[e]] + rank[e];
    unsigned short eb = __builtin_bit_cast(unsigned short, (_Float16)eattr[e]);
    ep4[pos] = (unsigned int)coli[e] | ((unsigned int)eb << 16);
}

// ---------------- output GEMM: LDS-staged f16 A, f32 out ----------------
__global__ __launch_bounds__(256) void gemm_out(const _Float16* __restrict__ Ah,
                                                const _Float16* __restrict__ Wfrag,
                                                const float* __restrict__ bo,
                                                float* __restrict__ C) {
    __shared__ _Float16 As[32 * LDSTRIDE];
    int tid = threadIdx.x;
    int wave = tid >> 6, lane = tid & 63;
    int m32 = lane & 31, quad = lane >> 5;
    int row0 = blockIdx.x * 32;

    {
        int r = tid >> 3;
        int c0 = (tid & 7) * 16;
        int gr = row0 + r;
        bool valid = gr < N_NODES;
        const v8h* src = (const v8h*)(Ah + (size_t)gr * 128 + c0);
        _Float16* dst = As + r * LDSTRIDE + c0;
        v8h z = {};
        *(v8h*)(dst) = valid ? src[0] : z;
        *(v8h*)(dst + 8) = valid ? src[1] : z;
    }
    __syncthreads();

    v8h af[8];
#pragma unroll
    for (int kt = 0; kt < 8; kt++)
        af[kt] = *(const v8h*)(As + m32 * LDSTRIDE + kt * 16 + quad * 8);

    int col = wave * 32 + m32;
    const _Float16* wf = Wfrag + 3 * 16384 + wave * 4096 + lane * 8;
    v16f acc;
#pragma unroll
    for (int r = 0; r < 16; r++) acc[r] = 0.0f;
#pragma unroll
    for (int kt = 0; kt < 8; kt++) {
        v8h bf = *(const v8h*)(wf + kt * 512);
        acc = __builtin_amdgcn_mfma_f32_32x32x16_f16(af[kt], bf, acc, 0, 0, 0);
    }
    float bias_v = bo[col];
#pragma unroll
    for (int r = 0; r < 16; r++) {
        int row = (r & 3) + 8 * (r >> 2) + 4 * quad;
        int gr = row0 + row;
        if (gr < N_NODES) C[(size_t)gr * 128 + col] = acc[r] + bias_v;
    }
}

// ---------------- fused attention: 16 lanes/node, K fp8 + V f16, 4B edge records ------
// R2 structure, K fp8 (R6: absmax 0.0098). Identity node order. no-max softmax (R1).
// Tail clamp to THIS node's last edge (e1-1). ep4: u16 col | f16 eattr.
__global__ __launch_bounds__(256) void fused_attn(const _Float16* __restrict__ Q,
                                                  const unsigned char* __restrict__ K8,
                                                  const _Float16* __restrict__ V,
                                                  const int* __restrict__ start,
                                                  const int* __restrict__ counts,
                                                  const unsigned int* __restrict__ ep4,
                                                  _Float16* __restrict__ Aout) {
    int t = blockIdx.x * 256 + threadIdx.x;
    int n = t >> 4;
    int sub = t & 15;
    if (n >= N_NODES) return;

    int s0 = start[n];
    int cnt = counts[n];
    int e1 = s0 + cnt;

    v8h_u q;
    q.v = *(const v8h*)(Q + (size_t)n * 128 + sub * 8);
    float qf[8];
#pragma unroll
    for (int j = 0; j < 8; j++) qf[j] = (float)q.e[j];

    const unsigned char* Kb = K8 + sub * 8;
    const _Float16* Vb = V + sub * 8;

    float l = 0.0f;
    float acc[8];
#pragma unroll
    for (int j = 0; j < 8; j++) acc[j] = 0.0f;

    int nb = (cnt + 15) >> 4;  // 16-edge super-blocks
    for (int b = 0; b < nb; b++) {
        int base = s0 + (b << 4);
        int li = base + sub;
        if (li >= e1) li = e1 - 1;
        unsigned int pv = ep4[li];

#pragma unroll
        for (int h = 0; h < 2; h++) {
            int hb = h << 3;
            if (base + hb < e1) {
                int cols[8];
                float eas[8];
#pragma unroll
                for (int u = 0; u < 8; u++) {
                    unsigned int w = (unsigned int)__shfl((int)pv, hb + u, 16);
                    cols[u] = (int)(w & 0xffffu);
                    eas[u] = (float)__builtin_bit_cast(_Float16, (unsigned short)(w >> 16));
                }
                // ---- load phase: 8x8B K + 8x16B V gathers, issued before any compute ----
                uint2 kw[8];
                v8h_u vv[8];
#pragma unroll
                for (int u = 0; u < 8; u++) {
                    kw[u] = *(const uint2*)(Kb + ((size_t)cols[u] << 7));
                    vv[u].v = *(const v8h*)(Vb + ((size_t)cols[u] << 7));
                }
                __builtin_amdgcn_sched_barrier(0);
                // ---- compute phase ----
#pragma unroll
                for (int u = 0; u < 8; u++) {
                    v2f k01 = cvt2_f8<false>(kw[u].x);
                    v2f k23 = cvt2_f8<true>(kw[u].x);
                    v2f k45 = cvt2_f8<false>(kw[u].y);
                    v2f k67 = cvt2_f8<true>(kw[u].y);
                    float dot = 0.0f;
                    dot = fmaf(qf[0], k01[0], dot);
                    dot = fmaf(qf[1], k01[1], dot);
                    dot = fmaf(qf[2], k23[0], dot);
                    dot = fmaf(qf[3], k23[1], dot);
                    dot = fmaf(qf[4], k45[0], dot);
                    dot = fmaf(qf[5], k45[1], dot);
                    dot = fmaf(qf[6], k67[0], dot);
                    dot = fmaf(qf[7], k67[1], dot);
                    dot += __shfl_xor(dot, 1);  // 2 lanes per head
                    float s = dot * 0.25f + eas[u];
                    bool valid = (base + hb + u) < e1;
                    float ex = valid ? __expf(s) : 0.0f;
                    l += ex;
#pragma unroll
                    for (int j = 0; j < 8; j++) acc[j] = fmaf(ex, (float)vv[u].e[j], acc[j]);
                }
            }
        }
    }

    float inv = 1.0f / (l + 1e-8f);
    _Float16 tmp[8];
#pragma unroll
    for (int j = 0; j < 8; j++) tmp[j] = (_Float16)(acc[j] * inv);
    *(v8h*)(Aout + (size_t)n * 128 + sub * 8) = *(v8h*)tmp;
}

extern "C" void kernel_launch(void* const* d_in, const int* in_sizes, int n_in,
                              void* d_out, int out_size, void* d_ws, size_t ws_size,
                              hipStream_t stream) {
    const float* x = (const float*)d_in[0];
    const int* ei = (const int*)d_in[1];
    const float* eattr = (const float*)d_in[2];
    const float* Wq = (const float*)d_in[3];
    const float* bq = (const float*)d_in[4];
    const float* Wk = (const float*)d_in[5];
    const float* bk = (const float*)d_in[6];
    const float* Wv = (const float*)d_in[7];
    const float* bv = (const float*)d_in[8];
    const float* Wo = (const float*)d_in[9];
    const float* bo = (const float*)d_in[10];
    float* out = (float*)d_out;

    const int* rowi = ei;
    const int* coli = ei + N_EDGES;

    // workspace carve
    _Float16* Qh = (_Float16*)d_ws;
    _Float16* Vh = Qh + (size_t)N_NODES * DIM;
    _Float16* Ah = Vh + (size_t)N_NODES * DIM;
    unsigned char* K8 = (unsigned char*)(Ah + (size_t)N_NODES * DIM);
    _Float16* Wfrag = (_Float16*)(K8 + (size_t)N_NODES * DIM);  // 4*16384 shorts
    int* counts = (int*)(Wfrag + 4 * 16384);
    int* start = counts + N_NODES;
    int* rank = start + N_NODES;
    int* cursor = rank + N_EDGES;
    unsigned int* ep4 = (unsigned int*)(cursor + 2);

    // 1. prep: zero counts/cursor + W frag layout
    prep_kernel<<<NBLK, 256, 0, stream>>>(Wq, Wk, Wv, Wo, Wfrag, counts, cursor);
    // 2. QKV projection || edge histogram (4-deep atomic MLP)
    qkv_hist<<<GBLK + HBLK, 256, 0, stream>>>(x, Wfrag, bq, bk, bv, Qh, K8, Vh,
                                              rowi, counts, rank);
    // 3. order-free segment allocation (block scan + cursor atomic)
    alloc_scan<<<NBLK, 256, 0, stream>>>(counts, start, cursor);
    // 4. atomic-free scatter (packed 4B records)
    scatter_k<<<EBLK, 256, 0, stream>>>(rowi, coli, eattr, start, rank, ep4);
    // 5. fused gather-attention (16 lanes per node, K fp8 + V f16)
    int ablocks = (N_NODES * 16 + 255) / 256;
    fused_attn<<<ablocks, 256, 0, stream>>>(Qh, K8, Vh, start, counts, ep4, Ah);
    // 6. output projection
    gemm_out<<<GBLK, 256, 0, stream>>>(Ah, Wfrag, bo, out);
}

// Round 9
// 191.496 us; speedup vs baseline: 1.3724x; 1.0002x over previous
//
#include <hip/hip_runtime.h>
#include <math.h>

#define N_NODES 50000
#define N_EDGES 600000
#define DIM 128
#define HEADS 8
#define NBLK 196
#define EBLK 2344   // (N_EDGES+255)/256
#define HBLK 586    // (N_EDGES+1023)/1024, 4 edges/thread
#define GBLK 1563   // (N_NODES+31)/32
#define CSTRIDE 16  // counters padded to one 64B line each (line-lock fix)

typedef _Float16 v8h __attribute__((ext_vector_type(8)));
typedef _Float16 v2h __attribute__((ext_vector_type(2)));
typedef float v16f __attribute__((ext_vector_type(16)));
typedef float v2f __attribute__((ext_vector_type(2)));

union v8h_u {
    v8h v;
    v2h p[4];
    _Float16 e[8];
};

// ---------------- fp8 e4m3 helpers (gfx950 HW cvt; OCP e4m3fn) ----------------
__device__ __forceinline__ float e4m3_to_f32_sw(unsigned int b) {
    unsigned int s = b >> 7, E = (b >> 3) & 0xF, m = b & 7;
    float v = (E == 0) ? (float)m * 0.001953125f
                       : ldexpf(1.0f + (float)m * 0.125f, (int)E - 7);
    return s ? -v : v;
}

template <bool HI>
__device__ __forceinline__ v2f cvt2_f8(unsigned int w) {
#if __has_builtin(__builtin_amdgcn_cvt_pk_f32_fp8)
    return __builtin_amdgcn_cvt_pk_f32_fp8((int)w, HI);
#else
    v2f r;
    r[0] = e4m3_to_f32_sw((w >> (HI ? 16 : 0)) & 0xff);
    r[1] = e4m3_to_f32_sw((w >> (HI ? 24 : 8)) & 0xff);
    return r;
#endif
}

__device__ __forceinline__ unsigned char f32_to_e4m3(float v) {
#if __has_builtin(__builtin_amdgcn_cvt_pk_fp8_f32)
    return (unsigned char)(__builtin_amdgcn_cvt_pk_fp8_f32(v, v, 0, false) & 0xff);
#else
    float a = fabsf(v);
    unsigned char sgn = (v < 0.f) ? 0x80 : 0;
    if (!(a >= 0.0078125f)) {
        int m = (int)(a * 512.0f + 0.5f);
        if (m > 7) return sgn | 8;
        return sgn | (unsigned char)m;
    }
    if (a >= 448.0f) return sgn | 0x7e;
    int e;
    float fr = frexpf(a, &e);
    int mant = (int)(fr * 16.0f + 0.5f);
    int E = e + 6;
    if (mant == 16) { mant = 8; E++; }
    if (E >= 16) return sgn | 0x7e;
    return sgn | (unsigned char)((E << 3) | (mant - 8));
#endif
}

// ---------------- prep: zero padded counts + cursor + W to MFMA-frag layout ----------------
__global__ __launch_bounds__(256) void prep_kernel(const float* __restrict__ Wq,
                                                   const float* __restrict__ Wk,
                                                   const float* __restrict__ Wv,
                                                   const float* __restrict__ Wo,
                                                   _Float16* __restrict__ Wfrag,
                                                   int* __restrict__ counts,
                                                   int* __restrict__ cursor) {
    int i = blockIdx.x * 256 + threadIdx.x;
    if (i < N_NODES) {
        // zero this node's padded counter line (64B)
        int4 z = make_int4(0, 0, 0, 0);
        int4* dst = (int4*)(counts + (size_t)i * CSTRIDE);
        dst[0] = z; dst[1] = z; dst[2] = z; dst[3] = z;
    }
    if (i == 0) cursor[0] = 0;
    if (i < 16384) {
        int base = i * 4;
        int mat = i >> 12;
        int rem = i & 4095;
        int wave = rem >> 10;
        int kt = (rem >> 7) & 7;
        int lane = (rem >> 1) & 63;
        int jh = (rem & 1) * 4;
        const float* src = (mat == 0) ? Wq : (mat == 1) ? Wk : (mat == 2) ? Wv : Wo;
        int n = wave * 32 + (lane & 31);
        int kbase = kt * 16 + (lane >> 5) * 8 + jh;
        _Float16 o[4];
#pragma unroll
        for (int j = 0; j < 4; j++) o[j] = (_Float16)src[(kbase + j) * 128 + n];
        *(short4*)(Wfrag + base) = *(short4*)o;
    }
}

// ---------------- fused QKV GEMM + edge histogram (independent work, one launch) ----
// blocks [0, GBLK): QKV projection (Q,V f16; K fp8)
// blocks [GBLK, GBLK+HBLK): hist, 4 edges/thread, PADDED counters (1 per 64B line):
// max ~12 serial RMWs per line instead of ~192 (line-lock hypothesis, R8 post-mortem).
#define LDSTRIDE 132
__global__ __launch_bounds__(256) void qkv_hist(const float* __restrict__ x,
                                                const _Float16* __restrict__ Wfrag,
                                                const float* __restrict__ bq,
                                                const float* __restrict__ bk,
                                                const float* __restrict__ bv,
                                                _Float16* __restrict__ Qh,
                                                unsigned char* __restrict__ K8,
                                                _Float16* __restrict__ Vh,
                                                const int* __restrict__ rowi,
                                                int* __restrict__ counts,
                                                int* __restrict__ rank) {
    __shared__ _Float16 As[32 * LDSTRIDE];
    if (blockIdx.x >= GBLK) {
        int e0 = (blockIdx.x - GBLK) * 1024 + threadIdx.x;
        int r[4], rk[4];
#pragma unroll
        for (int k = 0; k < 4; k++) {
            int e = e0 + k * 256;
            r[k] = (e < N_EDGES) ? rowi[e] : -1;
        }
#pragma unroll
        for (int k = 0; k < 4; k++)
            if (r[k] >= 0) rk[k] = atomicAdd(counts + (size_t)r[k] * CSTRIDE, 1);
#pragma unroll
        for (int k = 0; k < 4; k++) {
            int e = e0 + k * 256;
            if (e < N_EDGES) rank[e] = rk[k];
        }
        return;
    }
    int tid = threadIdx.x;
    int wave = tid >> 6, lane = tid & 63;
    int m32 = lane & 31, quad = lane >> 5;
    int row0 = blockIdx.x * 32;

    {
        int r = tid >> 3;
        int c0 = (tid & 7) * 16;
        int gr = row0 + r;
        bool valid = gr < N_NODES;
        const float4* src = (const float4*)(x + (size_t)gr * 128 + c0);
        _Float16* dst = As + r * LDSTRIDE + c0;
#pragma unroll
        for (int q = 0; q < 4; q++) {
            float4 v = valid ? src[q] : make_float4(0.f, 0.f, 0.f, 0.f);
            _Float16 o[4] = {(_Float16)v.x, (_Float16)v.y, (_Float16)v.z, (_Float16)v.w};
            *(short4*)(dst + q * 4) = *(short4*)o;
        }
    }
    __syncthreads();

    v8h af[8];
#pragma unroll
    for (int kt = 0; kt < 8; kt++)
        af[kt] = *(const v8h*)(As + m32 * LDSTRIDE + kt * 16 + quad * 8);

    int col = wave * 32 + m32;
#pragma unroll
    for (int mat = 0; mat < 3; mat++) {
        const _Float16* wf = Wfrag + mat * 16384 + wave * 4096 + lane * 8;
        v16f acc;
#pragma unroll
        for (int r = 0; r < 16; r++) acc[r] = 0.0f;
#pragma unroll
        for (int kt = 0; kt < 8; kt++) {
            v8h bf = *(const v8h*)(wf + kt * 512);
            acc = __builtin_amdgcn_mfma_f32_32x32x16_f16(af[kt], bf, acc, 0, 0, 0);
        }
        const float* bias = (mat == 0) ? bq : (mat == 1) ? bk : bv;
        float bias_v = bias[col];
        if (mat == 1) {
#pragma unroll
            for (int r = 0; r < 16; r++) {
                int row = (r & 3) + 8 * (r >> 2) + 4 * quad;
                int gr = row0 + row;
                if (gr < N_NODES) K8[(size_t)gr * 128 + col] = f32_to_e4m3(acc[r] + bias_v);
            }
        } else {
            _Float16* C = (mat == 0) ? Qh : Vh;
#pragma unroll
            for (int r = 0; r < 16; r++) {
                int row = (r & 3) + 8 * (r >> 2) + 4 * quad;
                int gr = row0 + row;
                if (gr < N_NODES) C[(size_t)gr * 128 + col] = (_Float16)(acc[r] + bias_v);
            }
        }
    }
}

// ---------------- segment allocation: block LDS scan + one cursor atomic per block ----
__global__ __launch_bounds__(256) void alloc_scan(const int* __restrict__ counts,
                                                  int* __restrict__ start,
                                                  int* __restrict__ cursor) {
    __shared__ int sh[256];
    __shared__ int base;
    int t = threadIdx.x;
    int idx = blockIdx.x * 256 + t;
    int v = (idx < N_NODES) ? counts[(size_t)idx * CSTRIDE] : 0;
    sh[t] = v;
    __syncthreads();
    for (int off = 1; off < 256; off <<= 1) {
        int a = sh[t];
        int b = (t >= off) ? sh[t - off] : 0;
        __syncthreads();
        sh[t] = a + b;
        __syncthreads();
    }
    if (t == 255) base = atomicAdd(cursor, sh[255]);
    __syncthreads();
    if (idx < N_NODES) start[idx] = base + sh[t] - v;
}

// ---------------- scatter: atomic-free, packed 4B edge records ----------------
__global__ __launch_bounds__(256) void scatter_k(const int* __restrict__ rowi,
                                                 const int* __restrict__ coli,
                                                 const float* __restrict__ eattr,
                                                 const int* __restrict__ start,
                                                 const int* __restrict__ rank,
                                                 unsigned int* __restrict__ ep4) {
    int e = blockIdx.x * 256 + threadIdx.x;
    if (e >= N_EDGES) return;
    int pos = start[rowi[e]] + rank[e];
    unsigned short eb = __builtin_bit_cast(unsigned short, (_Float16)eattr[e]);
    ep4[pos] = (unsigned int)coli[e] | ((unsigned int)eb << 16);
}

// ---------------- output GEMM: LDS-staged f16 A, f32 out ----------------
__global__ __launch_bounds__(256) void gemm_out(const _Float16* __restrict__ Ah,
                                                const _Float16* __restrict__ Wfrag,
                                                const float* __restrict__ bo,
                                                float* __restrict__ C) {
    __shared__ _Float16 As[32 * LDSTRIDE];
    int tid = threadIdx.x;
    int wave = tid >> 6, lane = tid & 63;
    int m32 = lane & 31, quad = lane >> 5;
    int row0 = blockIdx.x * 32;

    {
        int r = tid >> 3;
        int c0 = (tid & 7) * 16;
        int gr = row0 + r;
        bool valid = gr < N_NODES;
        const v8h* src = (const v8h*)(Ah + (size_t)gr * 128 + c0);
        _Float16* dst = As + r * LDSTRIDE + c0;
        v8h z = {};
        *(v8h*)(dst) = valid ? src[0] : z;
        *(v8h*)(dst + 8) = valid ? src[1] : z;
    }
    __syncthreads();

    v8h af[8];
#pragma unroll
    for (int kt = 0; kt < 8; kt++)
        af[kt] = *(const v8h*)(As + m32 * LDSTRIDE + kt * 16 + quad * 8);

    int col = wave * 32 + m32;
    const _Float16* wf = Wfrag + 3 * 16384 + wave * 4096 + lane * 8;
    v16f acc;
#pragma unroll
    for (int r = 0; r < 16; r++) acc[r] = 0.0f;
#pragma unroll
    for (int kt = 0; kt < 8; kt++) {
        v8h bf = *(const v8h*)(wf + kt * 512);
        acc = __builtin_amdgcn_mfma_f32_32x32x16_f16(af[kt], bf, acc, 0, 0, 0);
    }
    float bias_v = bo[col];
#pragma unroll
    for (int r = 0; r < 16; r++) {
        int row = (r & 3) + 8 * (r >> 2) + 4 * quad;
        int gr = row0 + row;
        if (gr < N_NODES) C[(size_t)gr * 128 + col] = acc[r] + bias_v;
    }
}

// ---------------- fused attention: 16 lanes/node, K fp8 + V f16, 4B edge records ------
// R2 structure, K fp8 (R6: absmax 0.0098). Identity node order. no-max softmax (R1).
// Tail clamp to THIS node's last edge (e1-1). ep4: u16 col | f16 eattr.
// counts is padded (stride CSTRIDE).
__global__ __launch_bounds__(256) void fused_attn(const _Float16* __restrict__ Q,
                                                  const unsigned char* __restrict__ K8,
                                                  const _Float16* __restrict__ V,
                                                  const int* __restrict__ start,
                                                  const int* __restrict__ counts,
                                                  const unsigned int* __restrict__ ep4,
                                                  _Float16* __restrict__ Aout) {
    int t = blockIdx.x * 256 + threadIdx.x;
    int n = t >> 4;
    int sub = t & 15;
    if (n >= N_NODES) return;

    int s0 = start[n];
    int cnt = counts[(size_t)n * CSTRIDE];
    int e1 = s0 + cnt;

    v8h_u q;
    q.v = *(const v8h*)(Q + (size_t)n * 128 + sub * 8);
    float qf[8];
#pragma unroll
    for (int j = 0; j < 8; j++) qf[j] = (float)q.e[j];

    const unsigned char* Kb = K8 + sub * 8;
    const _Float16* Vb = V + sub * 8;

    float l = 0.0f;
    float acc[8];
#pragma unroll
    for (int j = 0; j < 8; j++) acc[j] = 0.0f;

    int nb = (cnt + 15) >> 4;  // 16-edge super-blocks
    for (int b = 0; b < nb; b++) {
        int base = s0 + (b << 4);
        int li = base + sub;
        if (li >= e1) li = e1 - 1;
        unsigned int pv = ep4[li];

#pragma unroll
        for (int h = 0; h < 2; h++) {
            int hb = h << 3;
            if (base + hb < e1) {
                int cols[8];
                float eas[8];
#pragma unroll
                for (int u = 0; u < 8; u++) {
                    unsigned int w = (unsigned int)__shfl((int)pv, hb + u, 16);
                    cols[u] = (int)(w & 0xffffu);
                    eas[u] = (float)__builtin_bit_cast(_Float16, (unsigned short)(w >> 16));
                }
                // ---- load phase: 8x8B K + 8x16B V gathers, issued before any compute ----
                uint2 kw[8];
                v8h_u vv[8];
#pragma unroll
                for (int u = 0; u < 8; u++) {
                    kw[u] = *(const uint2*)(Kb + ((size_t)cols[u] << 7));
                    vv[u].v = *(const v8h*)(Vb + ((size_t)cols[u] << 7));
                }
                __builtin_amdgcn_sched_barrier(0);
                // ---- compute phase ----
#pragma unroll
                for (int u = 0; u < 8; u++) {
                    v2f k01 = cvt2_f8<false>(kw[u].x);
                    v2f k23 = cvt2_f8<true>(kw[u].x);
                    v2f k45 = cvt2_f8<false>(kw[u].y);
                    v2f k67 = cvt2_f8<true>(kw[u].y);
                    float dot = 0.0f;
                    dot = fmaf(qf[0], k01[0], dot);
                    dot = fmaf(qf[1], k01[1], dot);
                    dot = fmaf(qf[2], k23[0], dot);
                    dot = fmaf(qf[3], k23[1], dot);
                    dot = fmaf(qf[4], k45[0], dot);
                    dot = fmaf(qf[5], k45[1], dot);
                    dot = fmaf(qf[6], k67[0], dot);
                    dot = fmaf(qf[7], k67[1], dot);
                    dot += __shfl_xor(dot, 1);  // 2 lanes per head
                    float s = dot * 0.25f + eas[u];
                    bool valid = (base + hb + u) < e1;
                    float ex = valid ? __expf(s) : 0.0f;
                    l += ex;
#pragma unroll
                    for (int j = 0; j < 8; j++) acc[j] = fmaf(ex, (float)vv[u].e[j], acc[j]);
                }
            }
        }
    }

    float inv = 1.0f / (l + 1e-8f);
    _Float16 tmp[8];
#pragma unroll
    for (int j = 0; j < 8; j++) tmp[j] = (_Float16)(acc[j] * inv);
    *(v8h*)(Aout + (size_t)n * 128 + sub * 8) = *(v8h*)tmp;
}

extern "C" void kernel_launch(void* const* d_in, const int* in_sizes, int n_in,
                              void* d_out, int out_size, void* d_ws, size_t ws_size,
                              hipStream_t stream) {
    const float* x = (const float*)d_in[0];
    const int* ei = (const int*)d_in[1];
    const float* eattr = (const float*)d_in[2];
    const float* Wq = (const float*)d_in[3];
    const float* bq = (const float*)d_in[4];
    const float* Wk = (const float*)d_in[5];
    const float* bk = (const float*)d_in[6];
    const float* Wv = (const float*)d_in[7];
    const float* bv = (const float*)d_in[8];
    const float* Wo = (const float*)d_in[9];
    const float* bo = (const float*)d_in[10];
    float* out = (float*)d_out;

    const int* rowi = ei;
    const int* coli = ei + N_EDGES;

    // workspace carve
    _Float16* Qh = (_Float16*)d_ws;
    _Float16* Vh = Qh + (size_t)N_NODES * DIM;
    _Float16* Ah = Vh + (size_t)N_NODES * DIM;
    unsigned char* K8 = (unsigned char*)(Ah + (size_t)N_NODES * DIM);
    _Float16* Wfrag = (_Float16*)(K8 + (size_t)N_NODES * DIM);  // 4*16384 shorts
    int* counts = (int*)(Wfrag + 4 * 16384);                    // N_NODES * CSTRIDE ints
    int* start = counts + (size_t)N_NODES * CSTRIDE;
    int* rank = start + N_NODES;
    int* cursor = rank + N_EDGES;
    unsigned int* ep4 = (unsigned int*)(cursor + 2);

    // 1. prep: zero padded counts/cursor + W frag layout
    prep_kernel<<<NBLK, 256, 0, stream>>>(Wq, Wk, Wv, Wo, Wfrag, counts, cursor);
    // 2. QKV projection || edge histogram (padded counters)
    qkv_hist<<<GBLK + HBLK, 256, 0, stream>>>(x, Wfrag, bq, bk, bv, Qh, K8, Vh,
                                              rowi, counts, rank);
    // 3. order-free segment allocation (block scan + cursor atomic)
    alloc_scan<<<NBLK, 256, 0, stream>>>(counts, start, cursor);
    // 4. atomic-free scatter (packed 4B records)
    scatter_k<<<EBLK, 256, 0, stream>>>(rowi, coli, eattr, start, rank, ep4);
    // 5. fused gather-attention (16 lanes per node, K fp8 + V f16)
    int ablocks = (N_NODES * 16 + 255) / 256;
    fused_attn<<<ablocks, 256, 0, stream>>>(Qh, K8, Vh, start, counts, ep4, Ah);
    // 6. output projection
    gemm_out<<<GBLK, 256, 0, stream>>>(Ah, Wfrag, bo, out);
}

// Round 10
// 176.997 us; speedup vs baseline: 1.4849x; 1.0819x over previous
//
#include <hip/hip_runtime.h>
#include <math.h>

#define N_NODES 50000
#define N_EDGES 600000
#define DIM 128
#define HEADS 8
#define EBLK 2344   // (N_EDGES+255)/256
#define GBLK 1563   // (N_NODES+31)/32
#define NB1 586     // L1 sort blocks, 1024 edges each
#define L1E 1024

typedef _Float16 v8h __attribute__((ext_vector_type(8)));
typedef _Float16 v2h __attribute__((ext_vector_type(2)));
typedef float v16f __attribute__((ext_vector_type(16)));
typedef float v2f __attribute__((ext_vector_type(2)));

union v8h_u {
    v8h v;
    v2h p[4];
    _Float16 e[8];
};

// ---------------- fp8 e4m3 helpers (gfx950 HW cvt; OCP e4m3fn) ----------------
__device__ __forceinline__ float e4m3_to_f32_sw(unsigned int b) {
    unsigned int s = b >> 7, E = (b >> 3) & 0xF, m = b & 7;
    float v = (E == 0) ? (float)m * 0.001953125f
                       : ldexpf(1.0f + (float)m * 0.125f, (int)E - 7);
    return s ? -v : v;
}

template <bool HI>
__device__ __forceinline__ v2f cvt2_f8(unsigned int w) {
#if __has_builtin(__builtin_amdgcn_cvt_pk_f32_fp8)
    return __builtin_amdgcn_cvt_pk_f32_fp8((int)w, HI);
#else
    v2f r;
    r[0] = e4m3_to_f32_sw((w >> (HI ? 16 : 0)) & 0xff);
    r[1] = e4m3_to_f32_sw((w >> (HI ? 24 : 8)) & 0xff);
    return r;
#endif
}

__device__ __forceinline__ unsigned char f32_to_e4m3(float v) {
#if __has_builtin(__builtin_amdgcn_cvt_pk_fp8_f32)
    return (unsigned char)(__builtin_amdgcn_cvt_pk_fp8_f32(v, v, 0, false) & 0xff);
#else
    float a = fabsf(v);
    unsigned char sgn = (v < 0.f) ? 0x80 : 0;
    if (!(a >= 0.0078125f)) {
        int m = (int)(a * 512.0f + 0.5f);
        if (m > 7) return sgn | 8;
        return sgn | (unsigned char)m;
    }
    if (a >= 448.0f) return sgn | 0x7e;
    int e;
    float fr = frexpf(a, &e);
    int mant = (int)(fr * 16.0f + 0.5f);
    int E = e + 6;
    if (mant == 16) { mant = 8; E++; }
    if (E >= 16) return sgn | 0x7e;
    return sgn | (unsigned char)((E << 3) | (mant - 8));
#endif
}

// ---------------- prep: W to MFMA-frag layout (no counter zeroing needed) -------------
__global__ __launch_bounds__(256) void prep_kernel(const float* __restrict__ Wq,
                                                   const float* __restrict__ Wk,
                                                   const float* __restrict__ Wv,
                                                   const float* __restrict__ Wo,
                                                   _Float16* __restrict__ Wfrag) {
    int i = blockIdx.x * 256 + threadIdx.x;
    if (i < 16384) {
        int base = i * 4;
        int mat = i >> 12;
        int rem = i & 4095;
        int wave = rem >> 10;
        int kt = (rem >> 7) & 7;
        int lane = (rem >> 1) & 63;
        int jh = (rem & 1) * 4;
        const float* src = (mat == 0) ? Wq : (mat == 1) ? Wk : (mat == 2) ? Wv : Wo;
        int n = wave * 32 + (lane & 31);
        int kbase = kt * 16 + (lane >> 5) * 8 + jh;
        _Float16 o[4];
#pragma unroll
        for (int j = 0; j < 4; j++) o[j] = (_Float16)src[(kbase + j) * 128 + n];
        *(short4*)(Wfrag + base) = *(short4*)o;
    }
}

// ---------------- fused QKV GEMM + L1 coarse histogram (LDS atomics only) ----------
// blocks [0, GBLK): QKV projection (Q,V f16; K fp8)
// blocks [GBLK, GBLK+NB1): per-block LDS hist of coarse digit (row>>8) -> bh[d][b].
// ZERO global atomics (R8/R9: the 600K device-scope atomics were a fabric
// throughput wall ~18G RMW/s, insensitive to MLP and line padding).
#define LDSTRIDE 132
__global__ __launch_bounds__(256) void qkv_hist(const float* __restrict__ x,
                                                const _Float16* __restrict__ Wfrag,
                                                const float* __restrict__ bq,
                                                const float* __restrict__ bk,
                                                const float* __restrict__ bv,
                                                _Float16* __restrict__ Qh,
                                                unsigned char* __restrict__ K8,
                                                _Float16* __restrict__ Vh,
                                                const int* __restrict__ rowi,
                                                int* __restrict__ bh) {
    __shared__ _Float16 As[32 * LDSTRIDE];
    __shared__ int lh[256];
    if (blockIdx.x >= GBLK) {
        int b = blockIdx.x - GBLK;
        int t = threadIdx.x;
        lh[t] = 0;
        __syncthreads();
        int e0 = b * L1E + t;
#pragma unroll
        for (int k = 0; k < 4; k++) {
            int e = e0 + k * 256;
            if (e < N_EDGES) atomicAdd(lh + (rowi[e] >> 8), 1);
        }
        __syncthreads();
        bh[t * NB1 + b] = lh[t];
        return;
    }
    int tid = threadIdx.x;
    int wave = tid >> 6, lane = tid & 63;
    int m32 = lane & 31, quad = lane >> 5;
    int row0 = blockIdx.x * 32;

    {
        int r = tid >> 3;
        int c0 = (tid & 7) * 16;
        int gr = row0 + r;
        bool valid = gr < N_NODES;
        const float4* src = (const float4*)(x + (size_t)gr * 128 + c0);
        _Float16* dst = As + r * LDSTRIDE + c0;
#pragma unroll
        for (int q = 0; q < 4; q++) {
            float4 v = valid ? src[q] : make_float4(0.f, 0.f, 0.f, 0.f);
            _Float16 o[4] = {(_Float16)v.x, (_Float16)v.y, (_Float16)v.z, (_Float16)v.w};
            *(short4*)(dst + q * 4) = *(short4*)o;
        }
    }
    __syncthreads();

    v8h af[8];
#pragma unroll
    for (int kt = 0; kt < 8; kt++)
        af[kt] = *(const v8h*)(As + m32 * LDSTRIDE + kt * 16 + quad * 8);

    int col = wave * 32 + m32;
#pragma unroll
    for (int mat = 0; mat < 3; mat++) {
        const _Float16* wf = Wfrag + mat * 16384 + wave * 4096 + lane * 8;
        v16f acc;
#pragma unroll
        for (int r = 0; r < 16; r++) acc[r] = 0.0f;
#pragma unroll
        for (int kt = 0; kt < 8; kt++) {
            v8h bf = *(const v8h*)(wf + kt * 512);
            acc = __builtin_amdgcn_mfma_f32_32x32x16_f16(af[kt], bf, acc, 0, 0, 0);
        }
        const float* bias = (mat == 0) ? bq : (mat == 1) ? bk : bv;
        float bias_v = bias[col];
        if (mat == 1) {
#pragma unroll
            for (int r = 0; r < 16; r++) {
                int row = (r & 3) + 8 * (r >> 2) + 4 * quad;
                int gr = row0 + row;
                if (gr < N_NODES) K8[(size_t)gr * 128 + col] = f32_to_e4m3(acc[r] + bias_v);
            }
        } else {
            _Float16* C = (mat == 0) ? Qh : Vh;
#pragma unroll
            for (int r = 0; r < 16; r++) {
                int row = (r & 3) + 8 * (r >> 2) + 4 * quad;
                int gr = row0 + row;
                if (gr < N_NODES) C[(size_t)gr * 128 + col] = (_Float16)(acc[r] + bias_v);
            }
        }
    }
}

// ---------------- scanA: per-digit exclusive scan over blocks + digit totals ---------
__global__ __launch_bounds__(256) void scanA(const int* __restrict__ bh,
                                             int* __restrict__ within,
                                             int* __restrict__ dt) {
    __shared__ int sh[256];
    int d = blockIdx.x, t = threadIdx.x;
    int carry = 0;
    for (int c = 0; c < 3; c++) {
        int j = c * 256 + t;
        int v = (j < NB1) ? bh[d * NB1 + j] : 0;
        __syncthreads();
        sh[t] = v;
        __syncthreads();
        for (int off = 1; off < 256; off <<= 1) {
            int a = sh[t];
            int b2 = (t >= off) ? sh[t - off] : 0;
            __syncthreads();
            sh[t] = a + b2;
            __syncthreads();
        }
        if (j < NB1) within[d * NB1 + j] = carry + sh[t] - v;
        carry += sh[255];
    }
    if (t == 0) dt[d] = carry;
}

// ---------------- scanB: exclusive scan of 256 digit totals ----------------
__global__ __launch_bounds__(256) void scanB(const int* __restrict__ dt,
                                             int* __restrict__ dto) {
    __shared__ int sh[256];
    int t = threadIdx.x;
    int v = dt[t];
    sh[t] = v;
    __syncthreads();
    for (int off = 1; off < 256; off <<= 1) {
        int a = sh[t];
        int b2 = (t >= off) ? sh[t - off] : 0;
        __syncthreads();
        sh[t] = a + b2;
        __syncthreads();
    }
    dto[t] = sh[t] - v;
}

// ---------------- L1 scatter: coarse-bucket, LDS rank, atomic-free globally ----------
// rec1[pos] = row | col<<16 | f16(eattr)<<32
__global__ __launch_bounds__(256) void l1scat(const int* __restrict__ rowi,
                                              const int* __restrict__ coli,
                                              const float* __restrict__ eattr,
                                              const int* __restrict__ within,
                                              const int* __restrict__ dto,
                                              unsigned long long* __restrict__ rec1) {
    __shared__ int lh[256], base[256];
    int b = blockIdx.x, t = threadIdx.x;
    lh[t] = 0;
    base[t] = dto[t] + within[t * NB1 + b];
    __syncthreads();
    int e0 = b * L1E + t;
#pragma unroll
    for (int k = 0; k < 4; k++) {
        int e = e0 + k * 256;
        if (e < N_EDGES) {
            int row = rowi[e];
            int d = row >> 8;
            int r = atomicAdd(lh + d, 1);
            unsigned short eb = __builtin_bit_cast(unsigned short, (_Float16)eattr[e]);
            rec1[base[d] + r] = (unsigned long long)row |
                                ((unsigned long long)(unsigned int)coli[e] << 16) |
                                ((unsigned long long)eb << 32);
        }
    }
}

// ---------------- L2 sort: one block per coarse bucket; emits ep4 + counts/start -----
// node = (d<<8)|ld is unique per (bucket, low digit) -> counts/start written directly
// (covers all nodes < 50176, including zero-degree).
__global__ __launch_bounds__(256) void l2sort(const unsigned long long* __restrict__ rec1,
                                              const int* __restrict__ dto,
                                              const int* __restrict__ dt,
                                              int* __restrict__ counts,
                                              int* __restrict__ start,
                                              unsigned int* __restrict__ ep4) {
    __shared__ int h[256], hs[256], r2[256], sh[256];
    int d = blockIdx.x, t = threadIdx.x;
    int s = dto[d], cnt = dt[d];
    int e = s + cnt;
    h[t] = 0;
    r2[t] = 0;
    __syncthreads();
    for (int i = s + t; i < e; i += 256) atomicAdd(h + (int)(rec1[i] & 255), 1);
    __syncthreads();
    int v = h[t];
    sh[t] = v;
    __syncthreads();
    for (int off = 1; off < 256; off <<= 1) {
        int a = sh[t];
        int b2 = (t >= off) ? sh[t - off] : 0;
        __syncthreads();
        sh[t] = a + b2;
        __syncthreads();
    }
    int ex = sh[t] - v;  // exclusive prefix within bucket
    hs[t] = ex;
    int node = (d << 8) | t;
    if (node < N_NODES) {
        counts[node] = v;
        start[node] = s + ex;
    }
    __syncthreads();
    for (int i = s + t; i < e; i += 256) {
        unsigned long long w = rec1[i];
        int ld = (int)(w & 255);
        int r = atomicAdd(r2 + ld, 1);
        ep4[s + hs[ld] + r] = (unsigned int)(w >> 16);  // col | f16(eattr)<<16
    }
}

// ---------------- output GEMM: LDS-staged f16 A, f32 out ----------------
__global__ __launch_bounds__(256) void gemm_out(const _Float16* __restrict__ Ah,
                                                const _Float16* __restrict__ Wfrag,
                                                const float* __restrict__ bo,
                                                float* __restrict__ C) {
    __shared__ _Float16 As[32 * LDSTRIDE];
    int tid = threadIdx.x;
    int wave = tid >> 6, lane = tid & 63;
    int m32 = lane & 31, quad = lane >> 5;
    int row0 = blockIdx.x * 32;

    {
        int r = tid >> 3;
        int c0 = (tid & 7) * 16;
        int gr = row0 + r;
        bool valid = gr < N_NODES;
        const v8h* src = (const v8h*)(Ah + (size_t)gr * 128 + c0);
        _Float16* dst = As + r * LDSTRIDE + c0;
        v8h z = {};
        *(v8h*)(dst) = valid ? src[0] : z;
        *(v8h*)(dst + 8) = valid ? src[1] : z;
    }
    __syncthreads();

    v8h af[8];
#pragma unroll
    for (int kt = 0; kt < 8; kt++)
        af[kt] = *(const v8h*)(As + m32 * LDSTRIDE + kt * 16 + quad * 8);

    int col = wave * 32 + m32;
    const _Float16* wf = Wfrag + 3 * 16384 + wave * 4096 + lane * 8;
    v16f acc;
#pragma unroll
    for (int r = 0; r < 16; r++) acc[r] = 0.0f;
#pragma unroll
    for (int kt = 0; kt < 8; kt++) {
        v8h bf = *(const v8h*)(wf + kt * 512);
        acc = __builtin_amdgcn_mfma_f32_32x32x16_f16(af[kt], bf, acc, 0, 0, 0);
    }
    float bias_v = bo[col];
#pragma unroll
    for (int r = 0; r < 16; r++) {
        int row = (r & 3) + 8 * (r >> 2) + 4 * quad;
        int gr = row0 + row;
        if (gr < N_NODES) C[(size_t)gr * 128 + col] = acc[r] + bias_v;
    }
}

// ---------------- fused attention: 16 lanes/node, K fp8 + V f16, 4B edge records ------
// R2 structure, K fp8 (R6: absmax 0.0098). no-max softmax (R1). Tail clamp to
// THIS node's last edge (e1-1). ep4: u16 col | f16 eattr.
__global__ __launch_bounds__(256) void fused_attn(const _Float16* __restrict__ Q,
                                                  const unsigned char* __restrict__ K8,
                                                  const _Float16* __restrict__ V,
                                                  const int* __restrict__ start,
                                                  const int* __restrict__ counts,
                                                  const unsigned int* __restrict__ ep4,
                                                  _Float16* __restrict__ Aout) {
    int t = blockIdx.x * 256 + threadIdx.x;
    int n = t >> 4;
    int sub = t & 15;
    if (n >= N_NODES) return;

    int s0 = start[n];
    int cnt = counts[n];
    int e1 = s0 + cnt;

    v8h_u q;
    q.v = *(const v8h*)(Q + (size_t)n * 128 + sub * 8);
    float qf[8];
#pragma unroll
    for (int j = 0; j < 8; j++) qf[j] = (float)q.e[j];

    const unsigned char* Kb = K8 + sub * 8;
    const _Float16* Vb = V + sub * 8;

    float l = 0.0f;
    float acc[8];
#pragma unroll
    for (int j = 0; j < 8; j++) acc[j] = 0.0f;

    int nb = (cnt + 15) >> 4;  // 16-edge super-blocks
    for (int b = 0; b < nb; b++) {
        int base = s0 + (b << 4);
        int li = base + sub;
        if (li >= e1) li = e1 - 1;
        unsigned int pv = ep4[li];

#pragma unroll
        for (int h = 0; h < 2; h++) {
            int hb = h << 3;
            if (base + hb < e1) {
                int cols[8];
                float eas[8];
#pragma unroll
                for (int u = 0; u < 8; u++) {
                    unsigned int w = (unsigned int)__shfl((int)pv, hb + u, 16);
                    cols[u] = (int)(w & 0xffffu);
                    eas[u] = (float)__builtin_bit_cast(_Float16, (unsigned short)(w >> 16));
                }
                // ---- load phase: 8x8B K + 8x16B V gathers, issued before any compute ----
                uint2 kw[8];
                v8h_u vv[8];
#pragma unroll
                for (int u = 0; u < 8; u++) {
                    kw[u] = *(const uint2*)(Kb + ((size_t)cols[u] << 7));
                    vv[u].v = *(const v8h*)(Vb + ((size_t)cols[u] << 7));
                }
                __builtin_amdgcn_sched_barrier(0);
                // ---- compute phase ----
#pragma unroll
                for (int u = 0; u < 8; u++) {
                    v2f k01 = cvt2_f8<false>(kw[u].x);
                    v2f k23 = cvt2_f8<true>(kw[u].x);
                    v2f k45 = cvt2_f8<false>(kw[u].y);
                    v2f k67 = cvt2_f8<true>(kw[u].y);
                    float dot = 0.0f;
                    dot = fmaf(qf[0], k01[0], dot);
                    dot = fmaf(qf[1], k01[1], dot);
                    dot = fmaf(qf[2], k23[0], dot);
                    dot = fmaf(qf[3], k23[1], dot);
                    dot = fmaf(qf[4], k45[0], dot);
                    dot = fmaf(qf[5], k45[1], dot);
                    dot = fmaf(qf[6], k67[0], dot);
                    dot = fmaf(qf[7], k67[1], dot);
                    dot += __shfl_xor(dot, 1);  // 2 lanes per head
                    float s = dot * 0.25f + eas[u];
                    bool valid = (base + hb + u) < e1;
                    float ex = valid ? __expf(s) : 0.0f;
                    l += ex;
#pragma unroll
                    for (int j = 0; j < 8; j++) acc[j] = fmaf(ex, (float)vv[u].e[j], acc[j]);
                }
            }
        }
    }

    float inv = 1.0f / (l + 1e-8f);
    _Float16 tmp[8];
#pragma unroll
    for (int j = 0; j < 8; j++) tmp[j] = (_Float16)(acc[j] * inv);
    *(v8h*)(Aout + (size_t)n * 128 + sub * 8) = *(v8h*)tmp;
}

extern "C" void kernel_launch(void* const* d_in, const int* in_sizes, int n_in,
                              void* d_out, int out_size, void* d_ws, size_t ws_size,
                              hipStream_t stream) {
    const float* x = (const float*)d_in[0];
    const int* ei = (const int*)d_in[1];
    const float* eattr = (const float*)d_in[2];
    const float* Wq = (const float*)d_in[3];
    const float* bq = (const float*)d_in[4];
    const float* Wk = (const float*)d_in[5];
    const float* bk = (const float*)d_in[6];
    const float* Wv = (const float*)d_in[7];
    const float* bv = (const float*)d_in[8];
    const float* Wo = (const float*)d_in[9];
    const float* bo = (const float*)d_in[10];
    float* out = (float*)d_out;

    const int* rowi = ei;
    const int* coli = ei + N_EDGES;

    // workspace carve (rec1 offset is 8B-aligned by construction)
    _Float16* Qh = (_Float16*)d_ws;
    _Float16* Vh = Qh + (size_t)N_NODES * DIM;
    _Float16* Ah = Vh + (size_t)N_NODES * DIM;
    unsigned char* K8 = (unsigned char*)(Ah + (size_t)N_NODES * DIM);
    _Float16* Wfrag = (_Float16*)(K8 + (size_t)N_NODES * DIM);  // 4*16384 shorts
    int* counts = (int*)(Wfrag + 4 * 16384);
    int* start = counts + N_NODES;
    int* bh = start + N_NODES;            // 256*NB1
    int* within = bh + 256 * NB1;         // 256*NB1
    int* dt = within + 256 * NB1;         // 256
    int* dto = dt + 256;                  // 256
    unsigned long long* rec1 = (unsigned long long*)(dto + 256);  // N_EDGES u64
    unsigned int* ep4 = (unsigned int*)(rec1 + N_EDGES);

    // 1. prep: W frag layout
    prep_kernel<<<64, 256, 0, stream>>>(Wq, Wk, Wv, Wo, Wfrag);
    // 2. QKV projection || L1 coarse hist (LDS atomics only)
    qkv_hist<<<GBLK + NB1, 256, 0, stream>>>(x, Wfrag, bq, bk, bv, Qh, K8, Vh,
                                             rowi, bh);
    // 3. scans (within-digit over blocks; digit totals)
    scanA<<<256, 256, 0, stream>>>(bh, within, dt);
    scanB<<<1, 256, 0, stream>>>(dt, dto);
    // 4. L1 coarse scatter (atomic-free globally)
    l1scat<<<NB1, 256, 0, stream>>>(rowi, coli, eattr, within, dto, rec1);
    // 5. L2 in-bucket sort -> ep4 + counts/start
    l2sort<<<196, 256, 0, stream>>>(rec1, dto, dt, counts, start, ep4);
    // 6. fused gather-attention (16 lanes per node, K fp8 + V f16)
    int ablocks = (N_NODES * 16 + 255) / 256;
    fused_attn<<<ablocks, 256, 0, stream>>>(Qh, K8, Vh, start, counts, ep4, Ah);
    // 7. output projection
    gemm_out<<<GBLK, 256, 0, stream>>>(Ah, Wfrag, bo, out);
}